// Round 8
// baseline (206.065 us; speedup 1.0000x reference)
//
#include <hip/hip_runtime.h>
#include <hip/hip_bf16.h>
#include <stdint.h>

// Problem constants
#define K_TOK 2048
#define D_DIM 1024
#define H_N   16
#define DH_N  64
#define F_DIM 4096
#define S_SEQ 2048

typedef __attribute__((ext_vector_type(4))) float f32x4;
typedef __attribute__((ext_vector_type(8))) short bf16x8;

__device__ __forceinline__ float bf2f(ushort u) {
  union { unsigned u; float f; } c; c.u = ((unsigned)u) << 16; return c.f;
}
__device__ __forceinline__ ushort f2bf(float f) {
  union { float f; unsigned u; } c; c.f = f;
  unsigned x = c.u + 0x7fffu + ((c.u >> 16) & 1u);
  return (ushort)(x >> 16);
}

#define GLOAD_LDS16(GP, LP)                                                   \
  __builtin_amdgcn_global_load_lds(                                           \
      (const __attribute__((address_space(1))) unsigned int*)(GP),            \
      (__attribute__((address_space(3))) unsigned int*)(LP), 16, 0, 0)

// ---------------- fused weight prep: 7 transposes + bias concat ----------------
__global__ __launch_bounds__(256) void prep_all(
    const float* __restrict__ wq, const float* __restrict__ wk,
    const float* __restrict__ wv, const float* __restrict__ wo,
    const float* __restrict__ wg, const float* __restrict__ wu,
    const float* __restrict__ wd, const float* __restrict__ bq,
    const float* __restrict__ bk, const float* __restrict__ bv,
    ushort* __restrict__ qkvT, ushort* __restrict__ woT,
    ushort* __restrict__ guT, ushort* __restrict__ wdT,
    float* __restrict__ biasqkv) {
  __shared__ float tile[64][65];
  int b = blockIdx.x;
  if (b >= 4096) {
    int i = (b - 4096) * 256 + threadIdx.x;
    if (i < 3072)
      biasqkv[i] = (i < 1024) ? bq[i] : (i < 2048 ? bk[i - 1024] : bv[i - 2048]);
    return;
  }
  const float* src;
  ushort* dst;
  int C, mul, add, ldd, tid_tile;
  if (b < 1024) {
    int seg = b >> 8; tid_tile = b & 255; C = 1024; mul = 1; add = 0; ldd = 1024;
    if (seg == 0) { src = wq; dst = qkvT; }
    else if (seg == 1) { src = wk; dst = qkvT + 1024 * 1024; }
    else if (seg == 2) { src = wv; dst = qkvT + 2048 * 1024; }
    else { src = wo; dst = woT; }
  } else if (b < 2048) { src = wg; dst = guT; tid_tile = b - 1024; C = 4096; mul = 2; add = 0; ldd = 1024; }
  else if (b < 3072) { src = wu; dst = guT; tid_tile = b - 2048; C = 4096; mul = 2; add = 1; ldd = 1024; }
  else { src = wd; dst = wdT; tid_tile = b - 3072; C = 1024; mul = 1; add = 0; ldd = 4096; }

  int nbx = C >> 6;
  int bx = tid_tile % nbx, by = tid_tile / nbx;
  int c0 = bx << 6, r0 = by << 6;
  int tx = threadIdx.x & 15, ty = threadIdx.x >> 4;
#pragma unroll
  for (int i = 0; i < 4; ++i) {
    float4 v = *(const float4*)&src[(size_t)(r0 + ty + i * 16) * C + c0 + tx * 4];
    *(float4*)&tile[ty + i * 16][tx * 4] = v;
  }
  __syncthreads();
#pragma unroll
  for (int i = 0; i < 4; ++i) {
    int c = ty + i * 16;
    ushort4 o;
    o.x = f2bf(tile[tx * 4 + 0][c]);
    o.y = f2bf(tile[tx * 4 + 1][c]);
    o.z = f2bf(tile[tx * 4 + 2][c]);
    o.w = f2bf(tile[tx * 4 + 3][c]);
    *(ushort4*)&dst[(size_t)((c0 + c) * mul + add) * ldd + r0 + tx * 4] = o;
  }
}

// ---------------- fused: copy hidden->out [0,4096) | gather+RMSNorm1 [4096,6144) ----------------
__global__ __launch_bounds__(256) void gather_copy(
    const float* __restrict__ hs, const float* __restrict__ gating,
    const int* __restrict__ sel32, const int* __restrict__ pos32,
    const float* __restrict__ w, float* __restrict__ outc,
    float* __restrict__ xbuf, ushort* __restrict__ hbuf,
    float* __restrict__ gbuf, int* __restrict__ rowb, int* __restrict__ rowt,
    int* __restrict__ rowpos) {
  __shared__ float red[4];
  int tid = threadIdx.x;
  if (blockIdx.x < 4096) {
    int idx = blockIdx.x * 256 + tid;
    ((float4*)outc)[idx] = ((const float4*)hs)[idx];
    return;
  }
  int i = blockIdx.x - 4096;
  bool is64 = (sel32[1] == 0 && sel32[3] == 0 && sel32[5] == 0);
  int sel = is64 ? sel32[2 * i] : sel32[i];
  int b = sel >> 11;
  int t = sel & 2047;
  const float4* src = (const float4*)(hs + ((size_t)b * S_SEQ + t) * D_DIM);
  float4 v = src[tid];
  float ss = v.x * v.x + v.y * v.y + v.z * v.z + v.w * v.w;
  for (int off = 32; off; off >>= 1) ss += __shfl_xor(ss, off);
  if ((tid & 63) == 0) red[tid >> 6] = ss;
  __syncthreads();
  float tot = red[0] + red[1] + red[2] + red[3];
  float rms = rsqrtf(tot * (1.f / 1024.f) + 1e-6f);
  ((float4*)(xbuf + (size_t)i * D_DIM))[tid] = v;
  float4 lw = ((const float4*)w)[tid];
  ushort4 hv;
  hv.x = f2bf(v.x * rms * lw.x); hv.y = f2bf(v.y * rms * lw.y);
  hv.z = f2bf(v.z * rms * lw.z); hv.w = f2bf(v.w * rms * lw.w);
  *(ushort4*)&hbuf[(size_t)i * D_DIM + tid * 4] = hv;
  if (tid == 0) {
    rowb[i] = b; rowt[i] = t;
    bool is64p = (pos32[1] == 0 && pos32[3] == 0 && pos32[5] == 0);
    int pidx = b * S_SEQ + t;
    rowpos[i] = is64p ? pos32[2 * pidx] : pos32[pidx];
    gbuf[i] = gating[pidx];
  }
}

// ---------------- rmsnorm fused with split-K reduce of o-proj + residual ----------------
__global__ __launch_bounds__(256) void rmsnorm_ep1(const float* __restrict__ xbuf,
                                                   const float* __restrict__ pb,
                                                   const float* __restrict__ w,
                                                   float* __restrict__ x1out,
                                                   ushort* __restrict__ h2out) {
  int i = blockIdx.x, tid = threadIdx.x;
  __shared__ float red[4];
  size_t e = (size_t)i * D_DIM;
  float4 v = ((const float4*)(xbuf + e))[tid];
  float4 p0 = ((const float4*)(pb + e))[tid];
  float4 p1 = ((const float4*)(pb + 2097152 + e))[tid];
  v.x += p0.x + p1.x; v.y += p0.y + p1.y; v.z += p0.z + p1.z; v.w += p0.w + p1.w;
  ((float4*)(x1out + e))[tid] = v;
  float ss = v.x * v.x + v.y * v.y + v.z * v.z + v.w * v.w;
  for (int off = 32; off; off >>= 1) ss += __shfl_xor(ss, off);
  if ((tid & 63) == 0) red[tid >> 6] = ss;
  __syncthreads();
  float tot = red[0] + red[1] + red[2] + red[3];
  float rms = rsqrtf(tot * (1.f / 1024.f) + 1e-6f);
  float4 lw = ((const float4*)w)[tid];
  ushort4 hv;
  hv.x = f2bf(v.x * rms * lw.x); hv.y = f2bf(v.y * rms * lw.y);
  hv.z = f2bf(v.z * rms * lw.z); hv.w = f2bf(v.w * rms * lw.w);
  *(ushort4*)&h2out[e + tid * 4] = hv;
}

// ---------------- final epilogue: sum 4 down-proj partials, gated update, scatter ----------------
__global__ __launch_bounds__(256) void ep3_k(const float* __restrict__ pb,
                                             const float* __restrict__ x1b,
                                             const float* __restrict__ xbuf,
                                             const float* __restrict__ gbuf,
                                             const int* __restrict__ rowb,
                                             const int* __restrict__ rowt,
                                             float* __restrict__ out) {
  int idx = blockIdx.x * 256 + threadIdx.x;
  int row = idx >> 8, c4 = idx & 255;
  size_t e = (size_t)row * D_DIM + c4 * 4;
  float4 s0 = *(const float4*)(pb + e);
  float4 s1 = *(const float4*)(pb + 2097152 + e);
  float4 s2 = *(const float4*)(pb + 2 * 2097152 + e);
  float4 s3 = *(const float4*)(pb + 3 * 2097152 + e);
  float4 x = *(const float4*)(xbuf + e);
  float4 x1 = *(const float4*)(x1b + e);
  float g = gbuf[row];
  float4 r;
  r.x = x.x + (x1.x + s0.x + s1.x + s2.x + s3.x - x.x) * g;
  r.y = x.y + (x1.y + s0.y + s1.y + s2.y + s3.y - x.y) * g;
  r.z = x.z + (x1.z + s0.z + s1.z + s2.z + s3.z - x.z) * g;
  r.w = x.w + (x1.w + s0.w + s1.w + s2.w + s3.w - x.w) * g;
  *(float4*)(out + ((size_t)rowb[row] * S_SEQ + rowt[row]) * D_DIM + c4 * 4) = r;
}

// ---------------- generic bf16 GEMM (128x128, BK=64, double-buffered pipeline) ----------------
template <int MODE>
__global__ __launch_bounds__(256) void gemm_bt(
    const ushort* __restrict__ A, const ushort* __restrict__ BT,
    int M, int N, int ldk, int kdeff, int per,
    const float* __restrict__ bias,
    ushort* __restrict__ outb, float* __restrict__ outf) {
  __shared__ ushort lA[2][128 * 64];
  __shared__ ushort lB[2][128 * 64];
  int tid = threadIdx.x;
  int lane = tid & 63, wid = tid >> 6;
  int kidx = blockIdx.x / per;
  int bid = blockIdx.x % per;
  int nbn = N >> 7;
  int tm = bid / nbn, tn = bid % nbn;
  int wr = wid >> 1, wc = wid & 1;
  f32x4 acc[4][4];
#pragma unroll
  for (int m = 0; m < 4; ++m)
#pragma unroll
    for (int n = 0; n < 4; ++n) acc[m][n] = (f32x4){0.f, 0.f, 0.f, 0.f};

  const ushort* Ab = A + (size_t)(tm * 128) * ldk + (size_t)kidx * kdeff;
  const ushort* Bb = BT + (size_t)(tn * 128) * ldk + (size_t)kidx * kdeff;
  int lr = lane & 15, lg = lane >> 4;
  int prow = lane >> 3;
  int pch = lane & 7;
  int nk = kdeff >> 6;

  auto STG = [&](int bi, int t) {
#pragma unroll
    for (int p = 0; p < 4; ++p) {
      int rb = p * 32 + wid * 8;
      int row = rb + prow;
      int g = pch ^ (row & 7);
      GLOAD_LDS16(Ab + (size_t)row * ldk + t * 64 + g * 8, &lA[bi][rb * 64]);
      GLOAD_LDS16(Bb + (size_t)row * ldk + t * 64 + g * 8, &lB[bi][rb * 64]);
    }
  };

  STG(0, 0);
  STG(1, 1);
  asm volatile("s_waitcnt vmcnt(8)" ::: "memory");
  __builtin_amdgcn_s_barrier();

  for (int t = 0; t < nk; ++t) {
    int c = t & 1;
    const char* bA = (const char*)&lA[c][0];
    const char* bB = (const char*)&lB[c][0];
    bf16x8 bfv[4][2], af[4];
#pragma unroll
    for (int n = 0; n < 4; ++n) {
      int row = wc * 64 + n * 16 + lr;
#pragma unroll
      for (int kk = 0; kk < 2; ++kk)
        bfv[n][kk] = *(const bf16x8*)(bB + row * 128 + ((kk * 64 + lg * 16) ^ ((row & 7) << 4)));
    }
#pragma unroll
    for (int m = 0; m < 4; ++m) {
      int row = wr * 64 + m * 16 + lr;
      af[m] = *(const bf16x8*)(bA + row * 128 + ((lg * 16) ^ ((row & 7) << 4)));
    }
    __builtin_amdgcn_s_setprio(1);
#pragma unroll
    for (int m = 0; m < 4; ++m)
#pragma unroll
      for (int n = 0; n < 4; ++n)
        acc[m][n] = __builtin_amdgcn_mfma_f32_16x16x32_bf16(af[m], bfv[n][0], acc[m][n], 0, 0, 0);
    __builtin_amdgcn_s_setprio(0);
#pragma unroll
    for (int m = 0; m < 4; ++m) {
      int row = wr * 64 + m * 16 + lr;
      af[m] = *(const bf16x8*)(bA + row * 128 + ((64 + lg * 16) ^ ((row & 7) << 4)));
    }
    asm volatile("s_waitcnt lgkmcnt(0)" ::: "memory");
    __builtin_amdgcn_s_barrier();
    if (t + 2 < nk) STG(c, t + 2);
    __builtin_amdgcn_sched_barrier(0);
    __builtin_amdgcn_s_setprio(1);
#pragma unroll
    for (int m = 0; m < 4; ++m)
#pragma unroll
      for (int n = 0; n < 4; ++n)
        acc[m][n] = __builtin_amdgcn_mfma_f32_16x16x32_bf16(af[m], bfv[n][1], acc[m][n], 0, 0, 0);
    __builtin_amdgcn_s_setprio(0);
    if (t < nk - 1) {
      if (t + 2 < nk)
        asm volatile("s_waitcnt vmcnt(8)" ::: "memory");
      else
        asm volatile("s_waitcnt vmcnt(0)" ::: "memory");
      __builtin_amdgcn_s_barrier();
    }
  }

#pragma unroll
  for (int m = 0; m < 4; ++m) {
#pragma unroll
    for (int n = 0; n < 4; ++n) {
#pragma unroll
      for (int r = 0; r < 4; ++r) {
        int gr = tm * 128 + wr * 64 + m * 16 + lg * 4 + r;
        int gc = tn * 128 + wc * 64 + n * 16 + lr;
        float val = acc[m][n][r];
        if (MODE == 0) {
          outb[(size_t)gr * N + gc] = f2bf(val + bias[gc]);
        } else {
          outf[((size_t)kidx * M + gr) * N + gc] = val;
        }
      }
    }
  }
}

// ---------------- 256x256 gate/up GEMM: BK=32, TRIPLE-buffered, no mid-loop drains ----------------
// LDS per tile: A,B each [128 R][64] (two 64B k-rows packed per 128B LDS row, chunk-XOR swizzled).
// Prefetch depth 2 (tiles t+1, t+2 in flight), counted vmcnt(8); 2 raw barriers/iter.
__global__ __launch_bounds__(512, 2) void gemm256_gu(const ushort* __restrict__ A,
                                                     const ushort* __restrict__ BT,
                                                     ushort* __restrict__ outb) {
  __shared__ ushort lA[3][128 * 64];
  __shared__ ushort lB[3][128 * 64];
  int tid = threadIdx.x, lane = tid & 63, wid = tid >> 6;
  int bid = blockIdx.x;
  int tn = (bid & 7) * 4 + ((bid >> 3) & 3);  // XCD (bid&7) owns 4 tn (B L2-resident)
  int tm = bid >> 5;
  int wm = wid >> 2, wn = wid & 3;
  int lr = lane & 15, lg = lane >> 4;
  const ushort* Ab = A + (size_t)(tm * 256) * 1024;
  const ushort* Bb = BT + (size_t)(tn * 256) * 1024;

  f32x4 acc[8][4];
#pragma unroll
  for (int m = 0; m < 8; ++m)
#pragma unroll
    for (int n = 0; n < 4; ++n) acc[m][n] = (f32x4){0.f, 0.f, 0.f, 0.f};

  int sR0 = wid * 8 + (lane >> 3);   // R row (j=0) this lane stages
  int scp = lane & 7;                // swizzled chunk c' this lane writes

  // stage tile t (A 16KB + B 16KB) into buffer bi: 4 gload_lds/thread.
  // content inverse-swizzled so LDS linear position (R, c') holds
  // global (row = 2R + (c>>2), kchunk = c&3) with c = c' ^ (R&7).
  auto STG = [&](int bi, int t) {
#pragma unroll
    for (int j = 0; j < 2; ++j) {
      int R = j * 64 + sR0;
      int c = scp ^ (R & 7);
      int grow = 2 * R + (c >> 2);
      int kch = c & 3;
      GLOAD_LDS16(Ab + (size_t)grow * 1024 + t * 32 + kch * 8, &lA[bi][(j * 64 + wid * 8) * 64]);
      GLOAD_LDS16(Bb + (size_t)grow * 1024 + t * 32 + kch * 8, &lB[bi][(j * 64 + wid * 8) * 64]);
    }
  };

  STG(0, 0);
  STG(1, 1);
  STG(2, 2);
  asm volatile("s_waitcnt vmcnt(8)" ::: "memory");  // tile 0 landed; 1,2 in flight
  __builtin_amdgcn_s_barrier();

  for (int t = 0; t < 32; ++t) {
    if (t > 0) {
      __builtin_amdgcn_s_barrier();            // #1: all waves consumed tile t-1
      __builtin_amdgcn_sched_barrier(0);
      if (t + 2 < 32) {
        STG((t + 2) % 3, t + 2);               // overwrite buf of tile t-1
        asm volatile("s_waitcnt vmcnt(8)" ::: "memory");  // tile t landed; t+1,t+2 in flight
      } else if (t + 1 < 32) {
        asm volatile("s_waitcnt vmcnt(4)" ::: "memory");  // tile t landed; t+1 in flight
      } else {
        asm volatile("s_waitcnt vmcnt(0)" ::: "memory");  // final tile
      }
      __builtin_amdgcn_s_barrier();            // #2: tile t visible to all waves
      __builtin_amdgcn_sched_barrier(0);
    }
    const char* bA = (const char*)&lA[t % 3][0];
    const char* bB = (const char*)&lB[t % 3][0];
    bf16x8 bf[4], af[8];
#pragma unroll
    for (int n = 0; n < 4; ++n) {
      int rho = wn * 64 + n * 16 + lr;
      int R = rho >> 1;
      int cc = ((rho & 1) * 4 + lg) ^ (R & 7);
      bf[n] = *(const bf16x8*)(bB + R * 128 + cc * 16);
    }
#pragma unroll
    for (int m = 0; m < 8; ++m) {
      int rho = wm * 128 + m * 16 + lr;
      int R = rho >> 1;
      int cc = ((rho & 1) * 4 + lg) ^ (R & 7);
      af[m] = *(const bf16x8*)(bA + R * 128 + cc * 16);
    }
    __builtin_amdgcn_s_setprio(1);
#pragma unroll
    for (int m = 0; m < 8; ++m)
#pragma unroll
      for (int n = 0; n < 4; ++n)
        acc[m][n] = __builtin_amdgcn_mfma_f32_16x16x32_bf16(af[m], bf[n], acc[m][n], 0, 0, 0);
    __builtin_amdgcn_s_setprio(0);
  }

  // epilogue: silu(gate)*up, interleaved cols
#pragma unroll
  for (int m = 0; m < 8; ++m) {
#pragma unroll
    for (int n = 0; n < 4; ++n) {
#pragma unroll
      for (int r = 0; r < 4; ++r) {
        int gr = tm * 256 + wm * 128 + m * 16 + lg * 4 + r;
        int gc = tn * 256 + wn * 64 + n * 16 + lr;
        float val = acc[m][n][r];
        float other = __shfl_xor(val, 1);
        if (!(lane & 1)) {
          float g = val, u = other;
          float a = g / (1.f + __expf(-g)) * u;
          outb[(size_t)gr * (F_DIM) + (gc >> 1)] = f2bf(a);
        }
      }
    }
  }
}

// ---------------- fused: RoPE [0,4096) | V transpose [4096,6144) ----------------
__global__ __launch_bounds__(256) void rope_vtrans(const ushort* __restrict__ qkv,
                                                   const int* __restrict__ rowpos,
                                                   ushort* __restrict__ qr,
                                                   ushort* __restrict__ kr,
                                                   ushort* __restrict__ vt) {
  __shared__ ushort tile[32][33];
  if (blockIdx.x < 4096) {
    int idx = blockIdx.x * 256 + threadIdx.x;
    int i = idx >> 9;
    int rem = idx & 511;
    int h = rem >> 5, d = rem & 31;
    float pos = (float)rowpos[i];
    float inv = __expf(-(float)d * (9.210340371976184f / 32.0f));
    float ang = pos * inv;
    float sn, cs;
    __sincosf(ang, &sn, &cs);
    size_t base = (size_t)i * 3072;
    float q1 = bf2f(qkv[base + h * 64 + d]);
    float q2 = bf2f(qkv[base + h * 64 + 32 + d]);
    float k1 = bf2f(qkv[base + 1024 + h * 64 + d]);
    float k2 = bf2f(qkv[base + 1024 + h * 64 + 32 + d]);
    size_t ob = ((size_t)h * K_TOK + i) * DH_N;
    qr[ob + d] = f2bf((q1 * cs - q2 * sn) * 0.125f);
    qr[ob + 32 + d] = f2bf((q2 * cs + q1 * sn) * 0.125f);
    kr[ob + d] = f2bf(k1 * cs - k2 * sn);
    kr[ob + 32 + d] = f2bf(k2 * cs + k1 * sn);
    return;
  }
  int bid = blockIdx.x - 4096;
  int bx = bid & 63, by = bid >> 6;
  int i0 = bx << 5, c0 = by << 5;
  int tx = threadIdx.x & 31, ty = threadIdx.x >> 5;
#pragma unroll
  for (int j = 0; j < 32; j += 8)
    tile[ty + j][tx] = qkv[(size_t)(i0 + ty + j) * 3072 + 2048 + c0 + tx];
  __syncthreads();
#pragma unroll
  for (int j = 0; j < 32; j += 8)
    vt[(size_t)(c0 + ty + j) * K_TOK + i0 + tx] = tile[tx][ty + j];
}

// ---------------- MFMA flash attention, split-K chunks ----------------
__global__ __launch_bounds__(256) void attn_mfma(const ushort* __restrict__ qr,
                                                 const ushort* __restrict__ kr,
                                                 const ushort* __restrict__ vt,
                                                 ushort* __restrict__ ows,
                                                 float* __restrict__ mlws) {
  __shared__ ushort ktile[2][64 * 64];
  __shared__ ushort vtile[2][64 * 64];
  __shared__ ushort pbuf[4][16 * 64];
  int tid = threadIdx.x, lane = tid & 63, wid = tid >> 6;
  int bid = blockIdx.x;
  int h = bid / 144;
  int rem = 143 - (bid % 144);
  int g = 0;
  while (rem >= 2 * (g + 1) * (g + 2)) ++g;
  int rem2 = rem - 2 * g * (g + 1);
  int qt = (g << 2) + rem2 / (g + 1);
  int ci = rem2 % (g + 1);
  int slot = h * 144 + rem;
  int q0 = qt << 6;
  int t0 = ci << 2;
  int t1 = min(t0 + 3, qt);

  const ushort* Kh = kr + (size_t)h * K_TOK * DH_N;
  const ushort* Vh = vt + (size_t)h * DH_N * K_TOK;
  int lr = lane & 15, lg = lane >> 4;
  int qbase = q0 + wid * 16;

  bf16x8 qf[2];
  const ushort* Qp = qr + ((size_t)h * K_TOK + qbase + lr) * DH_N + lg * 8;
  qf[0] = *(const bf16x8*)(Qp);
  qf[1] = *(const bf16x8*)(Qp + 32);

  f32x4 oa[4];
  float mreg[4], lreg[4];
#pragma unroll
  for (int ct = 0; ct < 4; ++ct) oa[ct] = (f32x4){0.f, 0.f, 0.f, 0.f};
#pragma unroll
  for (int r = 0; r < 4; ++r) { mreg[r] = -1e30f; lreg[r] = 0.f; }

  char* pws = (char*)&pbuf[wid][0];
  int srow8 = lane >> 3, schunk = lane & 7;

  auto stage = [&](int bi, int kb) {
#pragma unroll
    for (int j = 0; j < 2; ++j) {
      int rbase = wid * 16 + j * 8;
      int row = rbase + srow8;
      int gch = schunk ^ (row & 7);
      GLOAD_LDS16(Kh + (size_t)(kb + row) * DH_N + gch * 8, &ktile[bi][rbase * 64]);
      GLOAD_LDS16(Vh + (size_t)row * K_TOK + kb + gch * 8, &vtile[bi][rbase * 64]);
    }
  };

  stage(0, t0 << 6);
  int cur = 0;
  for (int t = t0; t <= t1; ++t) {
    int kb = t << 6;
    __syncthreads();
    if (t < t1) stage(cur ^ 1, (t + 1) << 6);

    const char* kt = (const char*)&ktile[cur][0];
    const char* vtl = (const char*)&vtile[cur][0];

    f32x4 sa[4];
#pragma unroll
    for (int ct = 0; ct < 4; ++ct) sa[ct] = (f32x4){0.f, 0.f, 0.f, 0.f};
#pragma unroll
    for (int s = 0; s < 2; ++s) {
#pragma unroll
      for (int ct = 0; ct < 4; ++ct) {
        int row = ct * 16 + lr;
        bf16x8 kf = *(const bf16x8*)(kt + row * 128 + ((s * 64 + lg * 16) ^ ((row & 7) << 4)));
        sa[ct] = __builtin_amdgcn_mfma_f32_16x16x32_bf16(qf[s], kf, sa[ct], 0, 0, 0);
      }
    }

#pragma unroll
    for (int r = 0; r < 4; ++r) {
      int q = qbase + lg * 4 + r;
      int prow = lg * 4 + r;
      float sv[4];
      float mx = mreg[r];
#pragma unroll
      for (int ct = 0; ct < 4; ++ct) {
        int key = kb + ct * 16 + lr;
        float x = sa[ct][r];
        sv[ct] = (key <= q) ? x : -1e30f;
        mx = fmaxf(mx, sv[ct]);
      }
      mx = fmaxf(mx, __shfl_xor(mx, 1));
      mx = fmaxf(mx, __shfl_xor(mx, 2));
      mx = fmaxf(mx, __shfl_xor(mx, 4));
      mx = fmaxf(mx, __shfl_xor(mx, 8));
      float resc = __expf(mreg[r] - mx);
      float ps = 0.f;
#pragma unroll
      for (int ct = 0; ct < 4; ++ct) {
        float p = __expf(sv[ct] - mx);
        ps += p;
        *(ushort*)(pws + prow * 128 + ((ct * 32 + lr * 2) ^ ((prow & 7) << 4))) = f2bf(p);
      }
      ps += __shfl_xor(ps, 1);
      ps += __shfl_xor(ps, 2);
      ps += __shfl_xor(ps, 4);
      ps += __shfl_xor(ps, 8);
      lreg[r] = lreg[r] * resc + ps;
      mreg[r] = mx;
#pragma unroll
      for (int ct = 0; ct < 4; ++ct) oa[ct][r] *= resc;
    }

    bf16x8 pf[2];
#pragma unroll
    for (int s = 0; s < 2; ++s)
      pf[s] = *(const bf16x8*)(pws + lr * 128 + ((s * 64 + lg * 16) ^ ((lr & 7) << 4)));
#pragma unroll
    for (int s = 0; s < 2; ++s) {
#pragma unroll
      for (int ct = 0; ct < 4; ++ct) {
        int row = ct * 16 + lr;
        bf16x8 vf = *(const bf16x8*)(vtl + row * 128 + ((s * 64 + lg * 16) ^ ((row & 7) << 4)));
        oa[ct] = __builtin_amdgcn_mfma_f32_16x16x32_bf16(pf[s], vf, oa[ct], 0, 0, 0);
      }
    }
    cur ^= 1;
  }

#pragma unroll
  for (int ct = 0; ct < 4; ++ct) {
#pragma unroll
    for (int r = 0; r < 4; ++r) {
      int prow = wid * 16 + lg * 4 + r;
      ows[(size_t)slot * 4096 + prow * 64 + ct * 16 + lr] = f2bf(oa[ct][r]);
    }
  }
  if (lr == 0) {
#pragma unroll
    for (int r = 0; r < 4; ++r) {
      int prow = wid * 16 + lg * 4 + r;
      mlws[(size_t)slot * 128 + prow] = mreg[r];
      mlws[(size_t)slot * 128 + 64 + prow] = lreg[r];
    }
  }
}

// ---------------- combine partial attention chunks ----------------
__global__ __launch_bounds__(256) void attn_combine(const ushort* __restrict__ ows,
                                                    const float* __restrict__ mlws,
                                                    ushort* __restrict__ aout) {
  int bid = blockIdx.x;
  int h = bid & 15, qt = bid >> 4;
  int g = qt >> 2;
  int nc = g + 1;
  int base = h * 144 + 2 * g * (g + 1) + (qt & 3) * nc;
  int tid = threadIdx.x;
  int row = tid >> 2, c0 = (tid & 3) * 16;
  float M = -1e30f;
  for (int i = 0; i < nc; ++i)
    M = fmaxf(M, mlws[(size_t)(base + i) * 128 + row]);
  float L = 0.f;
  float acc[16];
#pragma unroll
  for (int j = 0; j < 16; ++j) acc[j] = 0.f;
  for (int i = 0; i < nc; ++i) {
    size_t sl = (size_t)(base + i);
    float w = __expf(mlws[sl * 128 + row] - M);
    L += mlws[sl * 128 + 64 + row] * w;
    const bf16x8* op = (const bf16x8*)(ows + sl * 4096 + row * 64 + c0);
    bf16x8 v0 = op[0], v1 = op[1];
#pragma unroll
    for (int j = 0; j < 8; ++j) acc[j] += bf2f(((ushort)v0[j])) * w;
#pragma unroll
    for (int j = 0; j < 8; ++j) acc[8 + j] += bf2f(((ushort)v1[j])) * w;
  }
  float inv = 1.f / L;
  int q = qt * 64 + row;
  ushort* dst = aout + (size_t)q * D_DIM + h * DH_N + c0;
#pragma unroll
  for (int j = 0; j < 16; ++j) dst[j] = f2bf(acc[j] * inv);
}

// ---------------- launch ----------------
extern "C" void kernel_launch(void* const* d_in, const int* in_sizes, int n_in,
                              void* d_out, int out_size, void* d_ws, size_t ws_size,
                              hipStream_t stream) {
  const float* hs = (const float*)d_in[0];
  const float* gating = (const float*)d_in[1];
  const int* sel32 = (const int*)d_in[2];
  const int* pos32 = (const int*)d_in[3];
  const float* ln1w = (const float*)d_in[4];
  const float* ln2w = (const float*)d_in[5];
  const float* wq = (const float*)d_in[6];
  const float* bq = (const float*)d_in[7];
  const float* wk = (const float*)d_in[8];
  const float* bk = (const float*)d_in[9];
  const float* wv = (const float*)d_in[10];
  const float* bv = (const float*)d_in[11];
  const float* wo = (const float*)d_in[12];
  const float* wg = (const float*)d_in[13];
  const float* wu = (const float*)d_in[14];
  const float* wd = (const float*)d_in[15];
  float* out = (float*)d_out;

  char* wsb = (char*)d_ws;
  size_t off = 0;
  auto alloc = [&](size_t bytes) -> void* {
    void* p = wsb + off;
    off += (bytes + 255) & ~(size_t)255;
    return p;
  };
  ushort* qkvT = (ushort*)alloc(3072ull * 1024 * 2);
  ushort* woT = (ushort*)alloc(1024ull * 1024 * 2);
  ushort* guT = (ushort*)alloc(8192ull * 1024 * 2);
  ushort* wdT = (ushort*)alloc(1024ull * 4096 * 2);
  float* biasqkv = (float*)alloc(3072 * 4);
  float* xbuf = (float*)alloc(2048ull * 1024 * 4);
  // ---- region A: reused as split-K GEMM partial buffer (dead by gemm1/gemm3) ----
  ushort* hbuf = (ushort*)alloc(2048ull * 1024 * 2);
  ushort* qkv = (ushort*)alloc(2048ull * 3072 * 2);
  ushort* qrb = (ushort*)alloc(16ull * 2048 * 64 * 2);
  ushort* krb = (ushort*)alloc(16ull * 2048 * 64 * 2);
  ushort* vtb = (ushort*)alloc(16ull * 64 * 2048 * 2);
  ushort* aoutb = (ushort*)alloc(2048ull * 1024 * 2);
  float* pbuf = (float*)hbuf;
  // ---- region B: x1b/h2b/actb; doubles as attn partial store before rmsnorm_ep1 ----
  float* x1b = (float*)alloc(2048ull * 1024 * 4);
  ushort* h2b = (ushort*)alloc(2048ull * 1024 * 2);
  ushort* actb = (ushort*)alloc(2048ull * 4096 * 2);
  ushort* aows = (ushort*)x1b;
  float* amlws = (float*)((char*)x1b + 2304ull * 4096 * 2);
  float* gbuf = (float*)alloc(2048 * 4);
  int* rowb = (int*)alloc(2048 * 4);
  int* rowt = (int*)alloc(2048 * 4);
  int* rowpos = (int*)alloc(2048 * 4);
  if (off > ws_size) return;

  prep_all<<<4108, 256, 0, stream>>>(wq, wk, wv, wo, wg, wu, wd, bq, bk, bv, qkvT, woT, guT,
                                     wdT, biasqkv);
  gather_copy<<<6144, 256, 0, stream>>>(hs, gating, sel32, pos32, ln1w, out, xbuf, hbuf, gbuf,
                                        rowb, rowt, rowpos);
  gemm_bt<0><<<16 * 24, 256, 0, stream>>>(hbuf, qkvT, 2048, 3072, 1024, 1024, 16 * 24, biasqkv,
                                          qkv, nullptr);
  rope_vtrans<<<6144, 256, 0, stream>>>(qkv, rowpos, qrb, krb, vtb);
  attn_mfma<<<16 * 144, 256, 0, stream>>>(qrb, krb, vtb, aows, amlws);
  attn_combine<<<512, 256, 0, stream>>>(aows, amlws, aoutb);
  gemm_bt<4><<<2 * 16 * 8, 256, 0, stream>>>(aoutb, woT, 2048, 1024, 1024, 512, 16 * 8, nullptr,
                                             nullptr, pbuf);
  rmsnorm_ep1<<<2048, 256, 0, stream>>>(xbuf, pbuf, ln2w, x1b, h2b);
  gemm256_gu<<<256, 512, 0, stream>>>(h2b, guT, actb);
  gemm_bt<4><<<4 * 16 * 8, 256, 0, stream>>>(actb, wdT, 2048, 1024, 4096, 1024, 16 * 8, nullptr,
                                             nullptr, pbuf);
  ep3_k<<<2048, 256, 0, stream>>>(pbuf, x1b, xbuf, gbuf, rowb, rowt, out);
}

// Round 9
// 202.484 us; speedup vs baseline: 1.0177x; 1.0177x over previous
//
#include <hip/hip_runtime.h>
#include <hip/hip_bf16.h>
#include <stdint.h>

// Problem constants
#define K_TOK 2048
#define D_DIM 1024
#define H_N   16
#define DH_N  64
#define F_DIM 4096
#define S_SEQ 2048

typedef __attribute__((ext_vector_type(4))) float f32x4;
typedef __attribute__((ext_vector_type(8))) short bf16x8;

__device__ __forceinline__ float bf2f(ushort u) {
  union { unsigned u; float f; } c; c.u = ((unsigned)u) << 16; return c.f;
}
__device__ __forceinline__ ushort f2bf(float f) {
  union { float f; unsigned u; } c; c.f = f;
  unsigned x = c.u + 0x7fffu + ((c.u >> 16) & 1u);
  return (ushort)(x >> 16);
}

#define GLOAD_LDS16(GP, LP)                                                   \
  __builtin_amdgcn_global_load_lds(                                           \
      (const __attribute__((address_space(1))) unsigned int*)(GP),            \
      (__attribute__((address_space(3))) unsigned int*)(LP), 16, 0, 0)

// ---------------- fused weight prep: 7 transposes + bias concat ----------------
__global__ __launch_bounds__(256) void prep_all(
    const float* __restrict__ wq, const float* __restrict__ wk,
    const float* __restrict__ wv, const float* __restrict__ wo,
    const float* __restrict__ wg, const float* __restrict__ wu,
    const float* __restrict__ wd, const float* __restrict__ bq,
    const float* __restrict__ bk, const float* __restrict__ bv,
    ushort* __restrict__ qkvT, ushort* __restrict__ woT,
    ushort* __restrict__ guT, ushort* __restrict__ wdT,
    float* __restrict__ biasqkv) {
  __shared__ float tile[64][65];
  int b = blockIdx.x;
  if (b >= 4096) {
    int i = (b - 4096) * 256 + threadIdx.x;
    if (i < 3072)
      biasqkv[i] = (i < 1024) ? bq[i] : (i < 2048 ? bk[i - 1024] : bv[i - 2048]);
    return;
  }
  const float* src;
  ushort* dst;
  int C, mul, add, ldd, tid_tile;
  if (b < 1024) {
    int seg = b >> 8; tid_tile = b & 255; C = 1024; mul = 1; add = 0; ldd = 1024;
    if (seg == 0) { src = wq; dst = qkvT; }
    else if (seg == 1) { src = wk; dst = qkvT + 1024 * 1024; }
    else if (seg == 2) { src = wv; dst = qkvT + 2048 * 1024; }
    else { src = wo; dst = woT; }
  } else if (b < 2048) { src = wg; dst = guT; tid_tile = b - 1024; C = 4096; mul = 2; add = 0; ldd = 1024; }
  else if (b < 3072) { src = wu; dst = guT; tid_tile = b - 2048; C = 4096; mul = 2; add = 1; ldd = 1024; }
  else { src = wd; dst = wdT; tid_tile = b - 3072; C = 1024; mul = 1; add = 0; ldd = 4096; }

  int nbx = C >> 6;
  int bx = tid_tile % nbx, by = tid_tile / nbx;
  int c0 = bx << 6, r0 = by << 6;
  int tx = threadIdx.x & 15, ty = threadIdx.x >> 4;
#pragma unroll
  for (int i = 0; i < 4; ++i) {
    float4 v = *(const float4*)&src[(size_t)(r0 + ty + i * 16) * C + c0 + tx * 4];
    *(float4*)&tile[ty + i * 16][tx * 4] = v;
  }
  __syncthreads();
#pragma unroll
  for (int i = 0; i < 4; ++i) {
    int c = ty + i * 16;
    ushort4 o;
    o.x = f2bf(tile[tx * 4 + 0][c]);
    o.y = f2bf(tile[tx * 4 + 1][c]);
    o.z = f2bf(tile[tx * 4 + 2][c]);
    o.w = f2bf(tile[tx * 4 + 3][c]);
    *(ushort4*)&dst[(size_t)((c0 + c) * mul + add) * ldd + r0 + tx * 4] = o;
  }
}

// ---------------- fused: copy hidden->out [0,4096) | gather+RMSNorm1 [4096,6144) ----------------
__global__ __launch_bounds__(256) void gather_copy(
    const float* __restrict__ hs, const float* __restrict__ gating,
    const int* __restrict__ sel32, const int* __restrict__ pos32,
    const float* __restrict__ w, float* __restrict__ outc,
    float* __restrict__ xbuf, ushort* __restrict__ hbuf,
    float* __restrict__ gbuf, int* __restrict__ rowb, int* __restrict__ rowt,
    int* __restrict__ rowpos) {
  __shared__ float red[4];
  int tid = threadIdx.x;
  if (blockIdx.x < 4096) {
    int idx = blockIdx.x * 256 + tid;
    ((float4*)outc)[idx] = ((const float4*)hs)[idx];
    return;
  }
  int i = blockIdx.x - 4096;
  bool is64 = (sel32[1] == 0 && sel32[3] == 0 && sel32[5] == 0);
  int sel = is64 ? sel32[2 * i] : sel32[i];
  int b = sel >> 11;
  int t = sel & 2047;
  const float4* src = (const float4*)(hs + ((size_t)b * S_SEQ + t) * D_DIM);
  float4 v = src[tid];
  float ss = v.x * v.x + v.y * v.y + v.z * v.z + v.w * v.w;
  for (int off = 32; off; off >>= 1) ss += __shfl_xor(ss, off);
  if ((tid & 63) == 0) red[tid >> 6] = ss;
  __syncthreads();
  float tot = red[0] + red[1] + red[2] + red[3];
  float rms = rsqrtf(tot * (1.f / 1024.f) + 1e-6f);
  ((float4*)(xbuf + (size_t)i * D_DIM))[tid] = v;
  float4 lw = ((const float4*)w)[tid];
  ushort4 hv;
  hv.x = f2bf(v.x * rms * lw.x); hv.y = f2bf(v.y * rms * lw.y);
  hv.z = f2bf(v.z * rms * lw.z); hv.w = f2bf(v.w * rms * lw.w);
  *(ushort4*)&hbuf[(size_t)i * D_DIM + tid * 4] = hv;
  if (tid == 0) {
    rowb[i] = b; rowt[i] = t;
    bool is64p = (pos32[1] == 0 && pos32[3] == 0 && pos32[5] == 0);
    int pidx = b * S_SEQ + t;
    rowpos[i] = is64p ? pos32[2 * pidx] : pos32[pidx];
    gbuf[i] = gating[pidx];
  }
}

// ---------------- rmsnorm fused with split-K reduce of o-proj + residual ----------------
__global__ __launch_bounds__(256) void rmsnorm_ep1(const float* __restrict__ xbuf,
                                                   const float* __restrict__ pb,
                                                   const float* __restrict__ w,
                                                   float* __restrict__ x1out,
                                                   ushort* __restrict__ h2out) {
  int i = blockIdx.x, tid = threadIdx.x;
  __shared__ float red[4];
  size_t e = (size_t)i * D_DIM;
  float4 v = ((const float4*)(xbuf + e))[tid];
  float4 p0 = ((const float4*)(pb + e))[tid];
  float4 p1 = ((const float4*)(pb + 2097152 + e))[tid];
  v.x += p0.x + p1.x; v.y += p0.y + p1.y; v.z += p0.z + p1.z; v.w += p0.w + p1.w;
  ((float4*)(x1out + e))[tid] = v;
  float ss = v.x * v.x + v.y * v.y + v.z * v.z + v.w * v.w;
  for (int off = 32; off; off >>= 1) ss += __shfl_xor(ss, off);
  if ((tid & 63) == 0) red[tid >> 6] = ss;
  __syncthreads();
  float tot = red[0] + red[1] + red[2] + red[3];
  float rms = rsqrtf(tot * (1.f / 1024.f) + 1e-6f);
  float4 lw = ((const float4*)w)[tid];
  ushort4 hv;
  hv.x = f2bf(v.x * rms * lw.x); hv.y = f2bf(v.y * rms * lw.y);
  hv.z = f2bf(v.z * rms * lw.z); hv.w = f2bf(v.w * rms * lw.w);
  *(ushort4*)&h2out[e + tid * 4] = hv;
}

// ---------------- final epilogue: sum 4 down-proj partials, gated update, scatter ----------------
__global__ __launch_bounds__(256) void ep3_k(const float* __restrict__ pb,
                                             const float* __restrict__ x1b,
                                             const float* __restrict__ xbuf,
                                             const float* __restrict__ gbuf,
                                             const int* __restrict__ rowb,
                                             const int* __restrict__ rowt,
                                             float* __restrict__ out) {
  int idx = blockIdx.x * 256 + threadIdx.x;
  int row = idx >> 8, c4 = idx & 255;
  size_t e = (size_t)row * D_DIM + c4 * 4;
  float4 s0 = *(const float4*)(pb + e);
  float4 s1 = *(const float4*)(pb + 2097152 + e);
  float4 s2 = *(const float4*)(pb + 2 * 2097152 + e);
  float4 s3 = *(const float4*)(pb + 3 * 2097152 + e);
  float4 x = *(const float4*)(xbuf + e);
  float4 x1 = *(const float4*)(x1b + e);
  float g = gbuf[row];
  float4 r;
  r.x = x.x + (x1.x + s0.x + s1.x + s2.x + s3.x - x.x) * g;
  r.y = x.y + (x1.y + s0.y + s1.y + s2.y + s3.y - x.y) * g;
  r.z = x.z + (x1.z + s0.z + s1.z + s2.z + s3.z - x.z) * g;
  r.w = x.w + (x1.w + s0.w + s1.w + s2.w + s3.w - x.w) * g;
  *(float4*)(out + ((size_t)rowb[row] * S_SEQ + rowt[row]) * D_DIM + c4 * 4) = r;
}

// ---------------- generic bf16 GEMM (128x128, BK=64, double-buffered pipeline) ----------------
template <int MODE>
__global__ __launch_bounds__(256) void gemm_bt(
    const ushort* __restrict__ A, const ushort* __restrict__ BT,
    int M, int N, int ldk, int kdeff, int per,
    const float* __restrict__ bias,
    ushort* __restrict__ outb, float* __restrict__ outf) {
  __shared__ ushort lA[2][128 * 64];
  __shared__ ushort lB[2][128 * 64];
  int tid = threadIdx.x;
  int lane = tid & 63, wid = tid >> 6;
  int kidx = blockIdx.x / per;
  int bid = blockIdx.x % per;
  int nbn = N >> 7;
  int tm = bid / nbn, tn = bid % nbn;
  int wr = wid >> 1, wc = wid & 1;
  f32x4 acc[4][4];
#pragma unroll
  for (int m = 0; m < 4; ++m)
#pragma unroll
    for (int n = 0; n < 4; ++n) acc[m][n] = (f32x4){0.f, 0.f, 0.f, 0.f};

  const ushort* Ab = A + (size_t)(tm * 128) * ldk + (size_t)kidx * kdeff;
  const ushort* Bb = BT + (size_t)(tn * 128) * ldk + (size_t)kidx * kdeff;
  int lr = lane & 15, lg = lane >> 4;
  int prow = lane >> 3;
  int pch = lane & 7;
  int nk = kdeff >> 6;

  auto STG = [&](int bi, int t) {
#pragma unroll
    for (int p = 0; p < 4; ++p) {
      int rb = p * 32 + wid * 8;
      int row = rb + prow;
      int g = pch ^ (row & 7);
      GLOAD_LDS16(Ab + (size_t)row * ldk + t * 64 + g * 8, &lA[bi][rb * 64]);
      GLOAD_LDS16(Bb + (size_t)row * ldk + t * 64 + g * 8, &lB[bi][rb * 64]);
    }
  };

  STG(0, 0);
  STG(1, 1);
  asm volatile("s_waitcnt vmcnt(8)" ::: "memory");
  __builtin_amdgcn_s_barrier();

  for (int t = 0; t < nk; ++t) {
    int c = t & 1;
    const char* bA = (const char*)&lA[c][0];
    const char* bB = (const char*)&lB[c][0];
    bf16x8 bfv[4][2], af[4];
#pragma unroll
    for (int n = 0; n < 4; ++n) {
      int row = wc * 64 + n * 16 + lr;
#pragma unroll
      for (int kk = 0; kk < 2; ++kk)
        bfv[n][kk] = *(const bf16x8*)(bB + row * 128 + ((kk * 64 + lg * 16) ^ ((row & 7) << 4)));
    }
#pragma unroll
    for (int m = 0; m < 4; ++m) {
      int row = wr * 64 + m * 16 + lr;
      af[m] = *(const bf16x8*)(bA + row * 128 + ((lg * 16) ^ ((row & 7) << 4)));
    }
    __builtin_amdgcn_s_setprio(1);
#pragma unroll
    for (int m = 0; m < 4; ++m)
#pragma unroll
      for (int n = 0; n < 4; ++n)
        acc[m][n] = __builtin_amdgcn_mfma_f32_16x16x32_bf16(af[m], bfv[n][0], acc[m][n], 0, 0, 0);
    __builtin_amdgcn_s_setprio(0);
#pragma unroll
    for (int m = 0; m < 4; ++m) {
      int row = wr * 64 + m * 16 + lr;
      af[m] = *(const bf16x8*)(bA + row * 128 + ((64 + lg * 16) ^ ((row & 7) << 4)));
    }
    asm volatile("s_waitcnt lgkmcnt(0)" ::: "memory");
    __builtin_amdgcn_s_barrier();
    if (t + 2 < nk) STG(c, t + 2);
    __builtin_amdgcn_sched_barrier(0);
    __builtin_amdgcn_s_setprio(1);
#pragma unroll
    for (int m = 0; m < 4; ++m)
#pragma unroll
      for (int n = 0; n < 4; ++n)
        acc[m][n] = __builtin_amdgcn_mfma_f32_16x16x32_bf16(af[m], bfv[n][1], acc[m][n], 0, 0, 0);
    __builtin_amdgcn_s_setprio(0);
    if (t < nk - 1) {
      if (t + 2 < nk)
        asm volatile("s_waitcnt vmcnt(8)" ::: "memory");
      else
        asm volatile("s_waitcnt vmcnt(0)" ::: "memory");
      __builtin_amdgcn_s_barrier();
    }
  }

#pragma unroll
  for (int m = 0; m < 4; ++m) {
#pragma unroll
    for (int n = 0; n < 4; ++n) {
#pragma unroll
      for (int r = 0; r < 4; ++r) {
        int gr = tm * 128 + wr * 64 + m * 16 + lg * 4 + r;
        int gc = tn * 128 + wc * 64 + n * 16 + lr;
        float val = acc[m][n][r];
        if (MODE == 0) {
          outb[(size_t)gr * N + gc] = f2bf(val + bias[gc]);
        } else {
          outf[((size_t)kidx * M + gr) * N + gc] = val;
        }
      }
    }
  }
}

// ---------------- 256x256 gate/up GEMM: 8-phase k-slice pipeline (BK=64, dbuf) ----------------
// LDS [2 buf][2 kslice][128 R][64]: slice kk stores rows' k in [kk*32,kk*32+32);
// R-row packs global rows 2R,2R+1 (4 chunks each), chunk' = c ^ (R&7)  (0-conflict, R8-verified).
// 4 phases/K-tile: (kk,m-half). Each: {4-8 ds_read | stage 1 slice of t+1 | barrier |
// lgkm(0) | setprio 16 MFMA | barrier}. vmcnt(4) only at ph1/ph3 (never 0 mid-loop).
__global__ __launch_bounds__(512, 2) void gemm256_gu(const ushort* __restrict__ A,
                                                     const ushort* __restrict__ BT,
                                                     ushort* __restrict__ outb) {
  __shared__ ushort lA[2][2][128 * 64];
  __shared__ ushort lB[2][2][128 * 64];
  int tid = threadIdx.x, lane = tid & 63, wid = tid >> 6;
  int bid = blockIdx.x;
  int tn = (bid & 7) * 4 + ((bid >> 3) & 3);  // XCD (bid&7) owns 4 tn (B L2-resident)
  int tm = bid >> 5;
  int wm = wid >> 2, wn = wid & 3;
  int lr = lane & 15, lg = lane >> 4;
  const ushort* Ab = A + (size_t)(tm * 256) * 1024;
  const ushort* Bb = BT + (size_t)(tn * 256) * 1024;

  f32x4 acc[8][4];
#pragma unroll
  for (int m = 0; m < 8; ++m)
#pragma unroll
    for (int n = 0; n < 4; ++n) acc[m][n] = (f32x4){0.f, 0.f, 0.f, 0.f};

  int sR = lane >> 3;     // R within 8-R stripe
  int scp = lane & 7;     // chunk written (linear dest)

  // stage one 16KB k-slice (2 gloads/thread); inverse-swizzled source.
  auto STG_A = [&](int buf, int t, int kk) {
#pragma unroll
    for (int j = 0; j < 2; ++j) {
      int R = j * 64 + wid * 8 + sR;
      int c = scp ^ (R & 7);
      int grow = 2 * R + (c >> 2);
      GLOAD_LDS16(Ab + (size_t)grow * 1024 + t * 64 + kk * 32 + (c & 3) * 8,
                  &lA[buf][kk][(j * 64 + wid * 8) * 64]);
    }
  };
  auto STG_B = [&](int buf, int t, int kk) {
#pragma unroll
    for (int j = 0; j < 2; ++j) {
      int R = j * 64 + wid * 8 + sR;
      int c = scp ^ (R & 7);
      int grow = 2 * R + (c >> 2);
      GLOAD_LDS16(Bb + (size_t)grow * 1024 + t * 64 + kk * 32 + (c & 3) * 8,
                  &lB[buf][kk][(j * 64 + wid * 8) * 64]);
    }
  };

#define PH_BAR() { __builtin_amdgcn_s_barrier(); __builtin_amdgcn_sched_barrier(0); }

  // prologue: tile0 k0 (4 loads), tile0 k1 (4). vmcnt(4) -> k0 landed.
  STG_A(0, 0, 0); STG_B(0, 0, 0);
  STG_A(0, 0, 1); STG_B(0, 0, 1);
  asm volatile("s_waitcnt vmcnt(4)" ::: "memory");
  PH_BAR();

  for (int t = 0; t < 16; ++t) {
    int c = t & 1, o = c ^ 1;
    const char* a0 = (const char*)&lA[c][0][0];
    const char* a1 = (const char*)&lA[c][1][0];
    const char* b0 = (const char*)&lB[c][0][0];
    const char* b1 = (const char*)&lB[c][1][0];
    bf16x8 bf[4], af[4];

    // ---- ph0: kk0, rows m0-3 ----
#pragma unroll
    for (int n = 0; n < 4; ++n) {
      int rho = wn * 64 + n * 16 + lr; int R = rho >> 1;
      int cc = (((rho & 1) << 2) | lg) ^ (R & 7);
      bf[n] = *(const bf16x8*)(b0 + R * 128 + cc * 16);
    }
#pragma unroll
    for (int m = 0; m < 4; ++m) {
      int rho = wm * 128 + m * 16 + lr; int R = rho >> 1;
      int cc = (((rho & 1) << 2) | lg) ^ (R & 7);
      af[m] = *(const bf16x8*)(a0 + R * 128 + cc * 16);
    }
    if (t + 1 < 16) STG_A(o, t + 1, 0);
    PH_BAR();
    asm volatile("s_waitcnt lgkmcnt(0)" ::: "memory");
    __builtin_amdgcn_sched_barrier(0);
    __builtin_amdgcn_s_setprio(1);
#pragma unroll
    for (int m = 0; m < 4; ++m)
#pragma unroll
      for (int n = 0; n < 4; ++n)
        acc[m][n] = __builtin_amdgcn_mfma_f32_16x16x32_bf16(af[m], bf[n], acc[m][n], 0, 0, 0);
    __builtin_amdgcn_s_setprio(0);
    PH_BAR();

    // ---- ph1: kk0, rows m4-7 ----
#pragma unroll
    for (int m = 0; m < 4; ++m) {
      int rho = wm * 128 + 64 + m * 16 + lr; int R = rho >> 1;
      int cc = (((rho & 1) << 2) | lg) ^ (R & 7);
      af[m] = *(const bf16x8*)(a0 + R * 128 + cc * 16);
    }
    if (t + 1 < 16) {
      STG_B(o, t + 1, 0);
      asm volatile("s_waitcnt vmcnt(4)" ::: "memory");  // t's k1 landed
    } else {
      asm volatile("s_waitcnt vmcnt(0)" ::: "memory");  // last tile: drain k1
    }
    PH_BAR();
    asm volatile("s_waitcnt lgkmcnt(0)" ::: "memory");
    __builtin_amdgcn_sched_barrier(0);
    __builtin_amdgcn_s_setprio(1);
#pragma unroll
    for (int m = 0; m < 4; ++m)
#pragma unroll
      for (int n = 0; n < 4; ++n)
        acc[4 + m][n] = __builtin_amdgcn_mfma_f32_16x16x32_bf16(af[m], bf[n], acc[4 + m][n], 0, 0, 0);
    __builtin_amdgcn_s_setprio(0);
    PH_BAR();

    // ---- ph2: kk1, rows m0-3 ----
#pragma unroll
    for (int n = 0; n < 4; ++n) {
      int rho = wn * 64 + n * 16 + lr; int R = rho >> 1;
      int cc = (((rho & 1) << 2) | lg) ^ (R & 7);
      bf[n] = *(const bf16x8*)(b1 + R * 128 + cc * 16);
    }
#pragma unroll
    for (int m = 0; m < 4; ++m) {
      int rho = wm * 128 + m * 16 + lr; int R = rho >> 1;
      int cc = (((rho & 1) << 2) | lg) ^ (R & 7);
      af[m] = *(const bf16x8*)(a1 + R * 128 + cc * 16);
    }
    if (t + 1 < 16) STG_A(o, t + 1, 1);
    PH_BAR();
    asm volatile("s_waitcnt lgkmcnt(0)" ::: "memory");
    __builtin_amdgcn_sched_barrier(0);
    __builtin_amdgcn_s_setprio(1);
#pragma unroll
    for (int m = 0; m < 4; ++m)
#pragma unroll
      for (int n = 0; n < 4; ++n)
        acc[m][n] = __builtin_amdgcn_mfma_f32_16x16x32_bf16(af[m], bf[n], acc[m][n], 0, 0, 0);
    __builtin_amdgcn_s_setprio(0);
    PH_BAR();

    // ---- ph3: kk1, rows m4-7 ----
#pragma unroll
    for (int m = 0; m < 4; ++m) {
      int rho = wm * 128 + 64 + m * 16 + lr; int R = rho >> 1;
      int cc = (((rho & 1) << 2) | lg) ^ (R & 7);
      af[m] = *(const bf16x8*)(a1 + R * 128 + cc * 16);
    }
    if (t + 1 < 16) {
      STG_B(o, t + 1, 1);
      asm volatile("s_waitcnt vmcnt(4)" ::: "memory");  // t+1's k0 landed
    }
    PH_BAR();
    asm volatile("s_waitcnt lgkmcnt(0)" ::: "memory");
    __builtin_amdgcn_sched_barrier(0);
    __builtin_amdgcn_s_setprio(1);
#pragma unroll
    for (int m = 0; m < 4; ++m)
#pragma unroll
      for (int n = 0; n < 4; ++n)
        acc[4 + m][n] = __builtin_amdgcn_mfma_f32_16x16x32_bf16(af[m], bf[n], acc[4 + m][n], 0, 0, 0);
    __builtin_amdgcn_s_setprio(0);
    PH_BAR();
  }
#undef PH_BAR

  // epilogue: silu(gate)*up, interleaved cols
#pragma unroll
  for (int m = 0; m < 8; ++m) {
#pragma unroll
    for (int n = 0; n < 4; ++n) {
#pragma unroll
      for (int r = 0; r < 4; ++r) {
        int gr = tm * 256 + wm * 128 + m * 16 + lg * 4 + r;
        int gc = tn * 256 + wn * 64 + n * 16 + lr;
        float val = acc[m][n][r];
        float other = __shfl_xor(val, 1);
        if (!(lane & 1)) {
          float g = val, u = other;
          float a = g / (1.f + __expf(-g)) * u;
          outb[(size_t)gr * (F_DIM) + (gc >> 1)] = f2bf(a);
        }
      }
    }
  }
}

// ---------------- fused: RoPE [0,4096) | V transpose [4096,6144) ----------------
__global__ __launch_bounds__(256) void rope_vtrans(const ushort* __restrict__ qkv,
                                                   const int* __restrict__ rowpos,
                                                   ushort* __restrict__ qr,
                                                   ushort* __restrict__ kr,
                                                   ushort* __restrict__ vt) {
  __shared__ ushort tile[32][33];
  if (blockIdx.x < 4096) {
    int idx = blockIdx.x * 256 + threadIdx.x;
    int i = idx >> 9;
    int rem = idx & 511;
    int h = rem >> 5, d = rem & 31;
    float pos = (float)rowpos[i];
    float inv = __expf(-(float)d * (9.210340371976184f / 32.0f));
    float ang = pos * inv;
    float sn, cs;
    __sincosf(ang, &sn, &cs);
    size_t base = (size_t)i * 3072;
    float q1 = bf2f(qkv[base + h * 64 + d]);
    float q2 = bf2f(qkv[base + h * 64 + 32 + d]);
    float k1 = bf2f(qkv[base + 1024 + h * 64 + d]);
    float k2 = bf2f(qkv[base + 1024 + h * 64 + 32 + d]);
    size_t ob = ((size_t)h * K_TOK + i) * DH_N;
    qr[ob + d] = f2bf((q1 * cs - q2 * sn) * 0.125f);
    qr[ob + 32 + d] = f2bf((q2 * cs + q1 * sn) * 0.125f);
    kr[ob + d] = f2bf(k1 * cs - k2 * sn);
    kr[ob + 32 + d] = f2bf(k2 * cs + k1 * sn);
    return;
  }
  int bid = blockIdx.x - 4096;
  int bx = bid & 63, by = bid >> 6;
  int i0 = bx << 5, c0 = by << 5;
  int tx = threadIdx.x & 31, ty = threadIdx.x >> 5;
#pragma unroll
  for (int j = 0; j < 32; j += 8)
    tile[ty + j][tx] = qkv[(size_t)(i0 + ty + j) * 3072 + 2048 + c0 + tx];
  __syncthreads();
#pragma unroll
  for (int j = 0; j < 32; j += 8)
    vt[(size_t)(c0 + ty + j) * K_TOK + i0 + tx] = tile[tx][ty + j];
}

// ---------------- MFMA flash attention, split-K chunks ----------------
__global__ __launch_bounds__(256) void attn_mfma(const ushort* __restrict__ qr,
                                                 const ushort* __restrict__ kr,
                                                 const ushort* __restrict__ vt,
                                                 ushort* __restrict__ ows,
                                                 float* __restrict__ mlws) {
  __shared__ ushort ktile[2][64 * 64];
  __shared__ ushort vtile[2][64 * 64];
  __shared__ ushort pbuf[4][16 * 64];
  int tid = threadIdx.x, lane = tid & 63, wid = tid >> 6;
  int bid = blockIdx.x;
  int h = bid / 144;
  int rem = 143 - (bid % 144);
  int g = 0;
  while (rem >= 2 * (g + 1) * (g + 2)) ++g;
  int rem2 = rem - 2 * g * (g + 1);
  int qt = (g << 2) + rem2 / (g + 1);
  int ci = rem2 % (g + 1);
  int slot = h * 144 + rem;
  int q0 = qt << 6;
  int t0 = ci << 2;
  int t1 = min(t0 + 3, qt);

  const ushort* Kh = kr + (size_t)h * K_TOK * DH_N;
  const ushort* Vh = vt + (size_t)h * DH_N * K_TOK;
  int lr = lane & 15, lg = lane >> 4;
  int qbase = q0 + wid * 16;

  bf16x8 qf[2];
  const ushort* Qp = qr + ((size_t)h * K_TOK + qbase + lr) * DH_N + lg * 8;
  qf[0] = *(const bf16x8*)(Qp);
  qf[1] = *(const bf16x8*)(Qp + 32);

  f32x4 oa[4];
  float mreg[4], lreg[4];
#pragma unroll
  for (int ct = 0; ct < 4; ++ct) oa[ct] = (f32x4){0.f, 0.f, 0.f, 0.f};
#pragma unroll
  for (int r = 0; r < 4; ++r) { mreg[r] = -1e30f; lreg[r] = 0.f; }

  char* pws = (char*)&pbuf[wid][0];
  int srow8 = lane >> 3, schunk = lane & 7;

  auto stage = [&](int bi, int kb) {
#pragma unroll
    for (int j = 0; j < 2; ++j) {
      int rbase = wid * 16 + j * 8;
      int row = rbase + srow8;
      int gch = schunk ^ (row & 7);
      GLOAD_LDS16(Kh + (size_t)(kb + row) * DH_N + gch * 8, &ktile[bi][rbase * 64]);
      GLOAD_LDS16(Vh + (size_t)row * K_TOK + kb + gch * 8, &vtile[bi][rbase * 64]);
    }
  };

  stage(0, t0 << 6);
  int cur = 0;
  for (int t = t0; t <= t1; ++t) {
    int kb = t << 6;
    __syncthreads();
    if (t < t1) stage(cur ^ 1, (t + 1) << 6);

    const char* kt = (const char*)&ktile[cur][0];
    const char* vtl = (const char*)&vtile[cur][0];

    f32x4 sa[4];
#pragma unroll
    for (int ct = 0; ct < 4; ++ct) sa[ct] = (f32x4){0.f, 0.f, 0.f, 0.f};
#pragma unroll
    for (int s = 0; s < 2; ++s) {
#pragma unroll
      for (int ct = 0; ct < 4; ++ct) {
        int row = ct * 16 + lr;
        bf16x8 kf = *(const bf16x8*)(kt + row * 128 + ((s * 64 + lg * 16) ^ ((row & 7) << 4)));
        sa[ct] = __builtin_amdgcn_mfma_f32_16x16x32_bf16(qf[s], kf, sa[ct], 0, 0, 0);
      }
    }

#pragma unroll
    for (int r = 0; r < 4; ++r) {
      int q = qbase + lg * 4 + r;
      int prow = lg * 4 + r;
      float sv[4];
      float mx = mreg[r];
#pragma unroll
      for (int ct = 0; ct < 4; ++ct) {
        int key = kb + ct * 16 + lr;
        float x = sa[ct][r];
        sv[ct] = (key <= q) ? x : -1e30f;
        mx = fmaxf(mx, sv[ct]);
      }
      mx = fmaxf(mx, __shfl_xor(mx, 1));
      mx = fmaxf(mx, __shfl_xor(mx, 2));
      mx = fmaxf(mx, __shfl_xor(mx, 4));
      mx = fmaxf(mx, __shfl_xor(mx, 8));
      float resc = __expf(mreg[r] - mx);
      float ps = 0.f;
#pragma unroll
      for (int ct = 0; ct < 4; ++ct) {
        float p = __expf(sv[ct] - mx);
        ps += p;
        *(ushort*)(pws + prow * 128 + ((ct * 32 + lr * 2) ^ ((prow & 7) << 4))) = f2bf(p);
      }
      ps += __shfl_xor(ps, 1);
      ps += __shfl_xor(ps, 2);
      ps += __shfl_xor(ps, 4);
      ps += __shfl_xor(ps, 8);
      lreg[r] = lreg[r] * resc + ps;
      mreg[r] = mx;
#pragma unroll
      for (int ct = 0; ct < 4; ++ct) oa[ct][r] *= resc;
    }

    bf16x8 pf[2];
#pragma unroll
    for (int s = 0; s < 2; ++s)
      pf[s] = *(const bf16x8*)(pws + lr * 128 + ((s * 64 + lg * 16) ^ ((lr & 7) << 4)));
#pragma unroll
    for (int s = 0; s < 2; ++s) {
#pragma unroll
      for (int ct = 0; ct < 4; ++ct) {
        int row = ct * 16 + lr;
        bf16x8 vf = *(const bf16x8*)(vtl + row * 128 + ((s * 64 + lg * 16) ^ ((row & 7) << 4)));
        oa[ct] = __builtin_amdgcn_mfma_f32_16x16x32_bf16(pf[s], vf, oa[ct], 0, 0, 0);
      }
    }
    cur ^= 1;
  }

#pragma unroll
  for (int ct = 0; ct < 4; ++ct) {
#pragma unroll
    for (int r = 0; r < 4; ++r) {
      int prow = wid * 16 + lg * 4 + r;
      ows[(size_t)slot * 4096 + prow * 64 + ct * 16 + lr] = f2bf(oa[ct][r]);
    }
  }
  if (lr == 0) {
#pragma unroll
    for (int r = 0; r < 4; ++r) {
      int prow = wid * 16 + lg * 4 + r;
      mlws[(size_t)slot * 128 + prow] = mreg[r];
      mlws[(size_t)slot * 128 + 64 + prow] = lreg[r];
    }
  }
}

// ---------------- combine partial attention chunks ----------------
__global__ __launch_bounds__(256) void attn_combine(const ushort* __restrict__ ows,
                                                    const float* __restrict__ mlws,
                                                    ushort* __restrict__ aout) {
  int bid = blockIdx.x;
  int h = bid & 15, qt = bid >> 4;
  int g = qt >> 2;
  int nc = g + 1;
  int base = h * 144 + 2 * g * (g + 1) + (qt & 3) * nc;
  int tid = threadIdx.x;
  int row = tid >> 2, c0 = (tid & 3) * 16;
  float M = -1e30f;
  for (int i = 0; i < nc; ++i)
    M = fmaxf(M, mlws[(size_t)(base + i) * 128 + row]);
  float L = 0.f;
  float acc[16];
#pragma unroll
  for (int j = 0; j < 16; ++j) acc[j] = 0.f;
  for (int i = 0; i < nc; ++i) {
    size_t sl = (size_t)(base + i);
    float w = __expf(mlws[sl * 128 + row] - M);
    L += mlws[sl * 128 + 64 + row] * w;
    const bf16x8* op = (const bf16x8*)(ows + sl * 4096 + row * 64 + c0);
    bf16x8 v0 = op[0], v1 = op[1];
#pragma unroll
    for (int j = 0; j < 8; ++j) acc[j] += bf2f(((ushort)v0[j])) * w;
#pragma unroll
    for (int j = 0; j < 8; ++j) acc[8 + j] += bf2f(((ushort)v1[j])) * w;
  }
  float inv = 1.f / L;
  int q = qt * 64 + row;
  ushort* dst = aout + (size_t)q * D_DIM + h * DH_N + c0;
#pragma unroll
  for (int j = 0; j < 16; ++j) dst[j] = f2bf(acc[j] * inv);
}

// ---------------- launch ----------------
extern "C" void kernel_launch(void* const* d_in, const int* in_sizes, int n_in,
                              void* d_out, int out_size, void* d_ws, size_t ws_size,
                              hipStream_t stream) {
  const float* hs = (const float*)d_in[0];
  const float* gating = (const float*)d_in[1];
  const int* sel32 = (const int*)d_in[2];
  const int* pos32 = (const int*)d_in[3];
  const float* ln1w = (const float*)d_in[4];
  const float* ln2w = (const float*)d_in[5];
  const float* wq = (const float*)d_in[6];
  const float* bq = (const float*)d_in[7];
  const float* wk = (const float*)d_in[8];
  const float* bk = (const float*)d_in[9];
  const float* wv = (const float*)d_in[10];
  const float* bv = (const float*)d_in[11];
  const float* wo = (const float*)d_in[12];
  const float* wg = (const float*)d_in[13];
  const float* wu = (const float*)d_in[14];
  const float* wd = (const float*)d_in[15];
  float* out = (float*)d_out;

  char* wsb = (char*)d_ws;
  size_t off = 0;
  auto alloc = [&](size_t bytes) -> void* {
    void* p = wsb + off;
    off += (bytes + 255) & ~(size_t)255;
    return p;
  };
  ushort* qkvT = (ushort*)alloc(3072ull * 1024 * 2);
  ushort* woT = (ushort*)alloc(1024ull * 1024 * 2);
  ushort* guT = (ushort*)alloc(8192ull * 1024 * 2);
  ushort* wdT = (ushort*)alloc(1024ull * 4096 * 2);
  float* biasqkv = (float*)alloc(3072 * 4);
  float* xbuf = (float*)alloc(2048ull * 1024 * 4);
  // ---- region A: reused as split-K GEMM partial buffer (dead by gemm1/gemm3) ----
  ushort* hbuf = (ushort*)alloc(2048ull * 1024 * 2);
  ushort* qkv = (ushort*)alloc(2048ull * 3072 * 2);
  ushort* qrb = (ushort*)alloc(16ull * 2048 * 64 * 2);
  ushort* krb = (ushort*)alloc(16ull * 2048 * 64 * 2);
  ushort* vtb = (ushort*)alloc(16ull * 64 * 2048 * 2);
  ushort* aoutb = (ushort*)alloc(2048ull * 1024 * 2);
  float* pbuf = (float*)hbuf;
  // ---- region B: x1b/h2b/actb; doubles as attn partial store before rmsnorm_ep1 ----
  float* x1b = (float*)alloc(2048ull * 1024 * 4);
  ushort* h2b = (ushort*)alloc(2048ull * 1024 * 2);
  ushort* actb = (ushort*)alloc(2048ull * 4096 * 2);
  ushort* aows = (ushort*)x1b;
  float* amlws = (float*)((char*)x1b + 2304ull * 4096 * 2);
  float* gbuf = (float*)alloc(2048 * 4);
  int* rowb = (int*)alloc(2048 * 4);
  int* rowt = (int*)alloc(2048 * 4);
  int* rowpos = (int*)alloc(2048 * 4);
  if (off > ws_size) return;

  prep_all<<<4108, 256, 0, stream>>>(wq, wk, wv, wo, wg, wu, wd, bq, bk, bv, qkvT, woT, guT,
                                     wdT, biasqkv);
  gather_copy<<<6144, 256, 0, stream>>>(hs, gating, sel32, pos32, ln1w, out, xbuf, hbuf, gbuf,
                                        rowb, rowt, rowpos);
  gemm_bt<0><<<16 * 24, 256, 0, stream>>>(hbuf, qkvT, 2048, 3072, 1024, 1024, 16 * 24, biasqkv,
                                          qkv, nullptr);
  rope_vtrans<<<6144, 256, 0, stream>>>(qkv, rowpos, qrb, krb, vtb);
  attn_mfma<<<16 * 144, 256, 0, stream>>>(qrb, krb, vtb, aows, amlws);
  attn_combine<<<512, 256, 0, stream>>>(aows, amlws, aoutb);
  gemm_bt<4><<<2 * 16 * 8, 256, 0, stream>>>(aoutb, woT, 2048, 1024, 1024, 512, 16 * 8, nullptr,
                                             nullptr, pbuf);
  rmsnorm_ep1<<<2048, 256, 0, stream>>>(xbuf, pbuf, ln2w, x1b, h2b);
  gemm256_gu<<<256, 512, 0, stream>>>(h2b, guT, actb);
  gemm_bt<4><<<4 * 16 * 8, 256, 0, stream>>>(actb, wdT, 2048, 1024, 4096, 1024, 16 * 8, nullptr,
                                             nullptr, pbuf);
  ep3_k<<<2048, 256, 0, stream>>>(pbuf, x1b, xbuf, gbuf, rowb, rowt, out);
}

// Round 10
// 188.920 us; speedup vs baseline: 1.0908x; 1.0718x over previous
//
#include <hip/hip_runtime.h>
#include <hip/hip_bf16.h>
#include <stdint.h>

// Problem constants
#define K_TOK 2048
#define D_DIM 1024
#define H_N   16
#define DH_N  64
#define F_DIM 4096
#define S_SEQ 2048
#define PSTRIDE 2097152  // 2048*1024 elements: one split-K partial slice (bf16)

typedef __attribute__((ext_vector_type(4))) float f32x4;
typedef __attribute__((ext_vector_type(8))) short bf16x8;

__device__ __forceinline__ float bf2f(ushort u) {
  union { unsigned u; float f; } c; c.u = ((unsigned)u) << 16; return c.f;
}
__device__ __forceinline__ ushort f2bf(float f) {
  union { float f; unsigned u; } c; c.f = f;
  unsigned x = c.u + 0x7fffu + ((c.u >> 16) & 1u);
  return (ushort)(x >> 16);
}

#define GLOAD_LDS16(GP, LP)                                                   \
  __builtin_amdgcn_global_load_lds(                                           \
      (const __attribute__((address_space(1))) unsigned int*)(GP),            \
      (__attribute__((address_space(3))) unsigned int*)(LP), 16, 0, 0)

// ---------------- fused prep (7 transposes + bias) | copy hidden->out | gather+RMSNorm1 ----
// blocks [0,4096): weight transpose tiles | [4096,4108): bias | [4108,8204): copy
// [8204,10252): gather+rmsnorm rows
__global__ __launch_bounds__(256) void prep_gather(
    const float* __restrict__ wq, const float* __restrict__ wk,
    const float* __restrict__ wv, const float* __restrict__ wo,
    const float* __restrict__ wg, const float* __restrict__ wu,
    const float* __restrict__ wd, const float* __restrict__ bq,
    const float* __restrict__ bk, const float* __restrict__ bv,
    const float* __restrict__ hs, const float* __restrict__ gating,
    const int* __restrict__ sel32, const int* __restrict__ pos32,
    const float* __restrict__ ln1w,
    ushort* __restrict__ qkvT, ushort* __restrict__ woT,
    ushort* __restrict__ guT, ushort* __restrict__ wdT,
    float* __restrict__ biasqkv, float* __restrict__ outc,
    float* __restrict__ xbuf, ushort* __restrict__ hbuf,
    float* __restrict__ gbuf, int* __restrict__ rowb, int* __restrict__ rowt,
    int* __restrict__ rowpos) {
  __shared__ float tile[64][65];
  __shared__ float red[4];
  int b = blockIdx.x, tid = threadIdx.x;

  if (b >= 8204) {                 // ---- gather + RMSNorm1 ----
    int i = b - 8204;
    bool is64 = (sel32[1] == 0 && sel32[3] == 0 && sel32[5] == 0);
    int sel = is64 ? sel32[2 * i] : sel32[i];
    int bb = sel >> 11;
    int t = sel & 2047;
    const float4* src = (const float4*)(hs + ((size_t)bb * S_SEQ + t) * D_DIM);
    float4 v = src[tid];
    float ss = v.x * v.x + v.y * v.y + v.z * v.z + v.w * v.w;
    for (int off = 32; off; off >>= 1) ss += __shfl_xor(ss, off);
    if ((tid & 63) == 0) red[tid >> 6] = ss;
    __syncthreads();
    float tot = red[0] + red[1] + red[2] + red[3];
    float rms = rsqrtf(tot * (1.f / 1024.f) + 1e-6f);
    ((float4*)(xbuf + (size_t)i * D_DIM))[tid] = v;
    float4 lw = ((const float4*)ln1w)[tid];
    ushort4 hv;
    hv.x = f2bf(v.x * rms * lw.x); hv.y = f2bf(v.y * rms * lw.y);
    hv.z = f2bf(v.z * rms * lw.z); hv.w = f2bf(v.w * rms * lw.w);
    *(ushort4*)&hbuf[(size_t)i * D_DIM + tid * 4] = hv;
    if (tid == 0) {
      rowb[i] = bb; rowt[i] = t;
      bool is64p = (pos32[1] == 0 && pos32[3] == 0 && pos32[5] == 0);
      int pidx = bb * S_SEQ + t;
      rowpos[i] = is64p ? pos32[2 * pidx] : pos32[pidx];
      gbuf[i] = gating[pidx];
    }
    return;
  }
  if (b >= 4108) {                 // ---- copy hidden -> out ----
    int idx = (b - 4108) * 256 + tid;
    ((float4*)outc)[idx] = ((const float4*)hs)[idx];
    return;
  }
  if (b >= 4096) {                 // ---- bias concat ----
    int i = (b - 4096) * 256 + tid;
    if (i < 3072)
      biasqkv[i] = (i < 1024) ? bq[i] : (i < 2048 ? bk[i - 1024] : bv[i - 2048]);
    return;
  }
  // ---- weight transpose ----
  const float* src;
  ushort* dst;
  int C, mul, add, ldd, tid_tile;
  if (b < 1024) {
    int seg = b >> 8; tid_tile = b & 255; C = 1024; mul = 1; add = 0; ldd = 1024;
    if (seg == 0) { src = wq; dst = qkvT; }
    else if (seg == 1) { src = wk; dst = qkvT + 1024 * 1024; }
    else if (seg == 2) { src = wv; dst = qkvT + 2048 * 1024; }
    else { src = wo; dst = woT; }
  } else if (b < 2048) { src = wg; dst = guT; tid_tile = b - 1024; C = 4096; mul = 2; add = 0; ldd = 1024; }
  else if (b < 3072) { src = wu; dst = guT; tid_tile = b - 2048; C = 4096; mul = 2; add = 1; ldd = 1024; }
  else { src = wd; dst = wdT; tid_tile = b - 3072; C = 1024; mul = 1; add = 0; ldd = 4096; }

  int nbx = C >> 6;
  int bx = tid_tile % nbx, by = tid_tile / nbx;
  int c0 = bx << 6, r0 = by << 6;
  int tx = tid & 15, ty = tid >> 4;
#pragma unroll
  for (int i = 0; i < 4; ++i) {
    float4 v = *(const float4*)&src[(size_t)(r0 + ty + i * 16) * C + c0 + tx * 4];
    *(float4*)&tile[ty + i * 16][tx * 4] = v;
  }
  __syncthreads();
#pragma unroll
  for (int i = 0; i < 4; ++i) {
    int c = ty + i * 16;
    ushort4 o;
    o.x = f2bf(tile[tx * 4 + 0][c]);
    o.y = f2bf(tile[tx * 4 + 1][c]);
    o.z = f2bf(tile[tx * 4 + 2][c]);
    o.w = f2bf(tile[tx * 4 + 3][c]);
    *(ushort4*)&dst[(size_t)((c0 + c) * mul + add) * ldd + r0 + tx * 4] = o;
  }
}

// ---------------- rmsnorm fused with split-K reduce of o-proj (bf16 partials) + residual ----
__global__ __launch_bounds__(256) void rmsnorm_ep1(const float* __restrict__ xbuf,
                                                   const ushort* __restrict__ pb,
                                                   const float* __restrict__ w,
                                                   float* __restrict__ x1out,
                                                   ushort* __restrict__ h2out) {
  int i = blockIdx.x, tid = threadIdx.x;
  __shared__ float red[4];
  size_t e = (size_t)i * D_DIM + tid * 4;
  float4 v = *(const float4*)(xbuf + e);
  ushort4 p0 = *(const ushort4*)(pb + e);
  ushort4 p1 = *(const ushort4*)(pb + PSTRIDE + e);
  v.x += bf2f(p0.x) + bf2f(p1.x);
  v.y += bf2f(p0.y) + bf2f(p1.y);
  v.z += bf2f(p0.z) + bf2f(p1.z);
  v.w += bf2f(p0.w) + bf2f(p1.w);
  *(float4*)(x1out + e) = v;
  float ss = v.x * v.x + v.y * v.y + v.z * v.z + v.w * v.w;
  for (int off = 32; off; off >>= 1) ss += __shfl_xor(ss, off);
  if ((tid & 63) == 0) red[tid >> 6] = ss;
  __syncthreads();
  float tot = red[0] + red[1] + red[2] + red[3];
  float rms = rsqrtf(tot * (1.f / 1024.f) + 1e-6f);
  float4 lw = ((const float4*)w)[tid];
  ushort4 hv;
  hv.x = f2bf(v.x * rms * lw.x); hv.y = f2bf(v.y * rms * lw.y);
  hv.z = f2bf(v.z * rms * lw.z); hv.w = f2bf(v.w * rms * lw.w);
  *(ushort4*)&h2out[e] = hv;
}

// ---------------- final epilogue: sum 4 bf16 down-proj partials, gated update, scatter ----
__global__ __launch_bounds__(256) void ep3_k(const ushort* __restrict__ pb,
                                             const float* __restrict__ x1b,
                                             const float* __restrict__ xbuf,
                                             const float* __restrict__ gbuf,
                                             const int* __restrict__ rowb,
                                             const int* __restrict__ rowt,
                                             float* __restrict__ out) {
  int idx = blockIdx.x * 256 + threadIdx.x;
  int row = idx >> 8, c4 = idx & 255;
  size_t e = (size_t)row * D_DIM + c4 * 4;
  ushort4 s0 = *(const ushort4*)(pb + e);
  ushort4 s1 = *(const ushort4*)(pb + PSTRIDE + e);
  ushort4 s2 = *(const ushort4*)(pb + 2 * PSTRIDE + e);
  ushort4 s3 = *(const ushort4*)(pb + 3 * PSTRIDE + e);
  float4 x = *(const float4*)(xbuf + e);
  float4 x1 = *(const float4*)(x1b + e);
  float g = gbuf[row];
  float4 r;
  r.x = x.x + (x1.x + bf2f(s0.x) + bf2f(s1.x) + bf2f(s2.x) + bf2f(s3.x) - x.x) * g;
  r.y = x.y + (x1.y + bf2f(s0.y) + bf2f(s1.y) + bf2f(s2.y) + bf2f(s3.y) - x.y) * g;
  r.z = x.z + (x1.z + bf2f(s0.z) + bf2f(s1.z) + bf2f(s2.z) + bf2f(s3.z) - x.z) * g;
  r.w = x.w + (x1.w + bf2f(s0.w) + bf2f(s1.w) + bf2f(s2.w) + bf2f(s3.w) - x.w) * g;
  *(float4*)(out + ((size_t)rowb[row] * S_SEQ + rowt[row]) * D_DIM + c4 * 4) = r;
}

// ---------------- generic bf16 GEMM (128x128, BK=64, double-buffered pipeline) ----------------
// MODE 0: +bias -> bf16 | MODE 4: bf16 partial slice [kidx]
template <int MODE>
__global__ __launch_bounds__(256) void gemm_bt(
    const ushort* __restrict__ A, const ushort* __restrict__ BT,
    int M, int N, int ldk, int kdeff, int per,
    const float* __restrict__ bias,
    ushort* __restrict__ outb) {
  __shared__ ushort lA[2][128 * 64];
  __shared__ ushort lB[2][128 * 64];
  int tid = threadIdx.x;
  int lane = tid & 63, wid = tid >> 6;
  int kidx = blockIdx.x / per;
  int bid = blockIdx.x % per;
  int nbn = N >> 7;
  int tm = bid / nbn, tn = bid % nbn;
  int wr = wid >> 1, wc = wid & 1;
  f32x4 acc[4][4];
#pragma unroll
  for (int m = 0; m < 4; ++m)
#pragma unroll
    for (int n = 0; n < 4; ++n) acc[m][n] = (f32x4){0.f, 0.f, 0.f, 0.f};

  const ushort* Ab = A + (size_t)(tm * 128) * ldk + (size_t)kidx * kdeff;
  const ushort* Bb = BT + (size_t)(tn * 128) * ldk + (size_t)kidx * kdeff;
  int lr = lane & 15, lg = lane >> 4;
  int prow = lane >> 3;
  int pch = lane & 7;
  int nk = kdeff >> 6;

  auto STG = [&](int bi, int t) {
#pragma unroll
    for (int p = 0; p < 4; ++p) {
      int rb = p * 32 + wid * 8;
      int row = rb + prow;
      int g = pch ^ (row & 7);
      GLOAD_LDS16(Ab + (size_t)row * ldk + t * 64 + g * 8, &lA[bi][rb * 64]);
      GLOAD_LDS16(Bb + (size_t)row * ldk + t * 64 + g * 8, &lB[bi][rb * 64]);
    }
  };

  STG(0, 0);
  STG(1, 1);
  asm volatile("s_waitcnt vmcnt(8)" ::: "memory");
  __builtin_amdgcn_s_barrier();

  for (int t = 0; t < nk; ++t) {
    int c = t & 1;
    const char* bA = (const char*)&lA[c][0];
    const char* bB = (const char*)&lB[c][0];
    bf16x8 bfv[4][2], af[4];
#pragma unroll
    for (int n = 0; n < 4; ++n) {
      int row = wc * 64 + n * 16 + lr;
#pragma unroll
      for (int kk = 0; kk < 2; ++kk)
        bfv[n][kk] = *(const bf16x8*)(bB + row * 128 + ((kk * 64 + lg * 16) ^ ((row & 7) << 4)));
    }
#pragma unroll
    for (int m = 0; m < 4; ++m) {
      int row = wr * 64 + m * 16 + lr;
      af[m] = *(const bf16x8*)(bA + row * 128 + ((lg * 16) ^ ((row & 7) << 4)));
    }
    __builtin_amdgcn_s_setprio(1);
#pragma unroll
    for (int m = 0; m < 4; ++m)
#pragma unroll
      for (int n = 0; n < 4; ++n)
        acc[m][n] = __builtin_amdgcn_mfma_f32_16x16x32_bf16(af[m], bfv[n][0], acc[m][n], 0, 0, 0);
    __builtin_amdgcn_s_setprio(0);
#pragma unroll
    for (int m = 0; m < 4; ++m) {
      int row = wr * 64 + m * 16 + lr;
      af[m] = *(const bf16x8*)(bA + row * 128 + ((64 + lg * 16) ^ ((row & 7) << 4)));
    }
    asm volatile("s_waitcnt lgkmcnt(0)" ::: "memory");
    __builtin_amdgcn_s_barrier();
    if (t + 2 < nk) STG(c, t + 2);
    __builtin_amdgcn_sched_barrier(0);
    __builtin_amdgcn_s_setprio(1);
#pragma unroll
    for (int m = 0; m < 4; ++m)
#pragma unroll
      for (int n = 0; n < 4; ++n)
        acc[m][n] = __builtin_amdgcn_mfma_f32_16x16x32_bf16(af[m], bfv[n][1], acc[m][n], 0, 0, 0);
    __builtin_amdgcn_s_setprio(0);
    if (t < nk - 1) {
      if (t + 2 < nk)
        asm volatile("s_waitcnt vmcnt(8)" ::: "memory");
      else
        asm volatile("s_waitcnt vmcnt(0)" ::: "memory");
      __builtin_amdgcn_s_barrier();
    }
  }

#pragma unroll
  for (int m = 0; m < 4; ++m) {
#pragma unroll
    for (int n = 0; n < 4; ++n) {
#pragma unroll
      for (int r = 0; r < 4; ++r) {
        int gr = tm * 128 + wr * 64 + m * 16 + lg * 4 + r;
        int gc = tn * 128 + wc * 64 + n * 16 + lr;
        float val = acc[m][n][r];
        if (MODE == 0) {
          outb[(size_t)gr * N + gc] = f2bf(val + bias[gc]);
        } else {
          outb[(size_t)kidx * PSTRIDE + (size_t)gr * N + gc] = f2bf(val);
        }
      }
    }
  }
}

// ---------------- 256x256 pipelined GEMM for gate/up (R7 version, best measured) ----------------
__global__ __launch_bounds__(512, 2) void gemm256_gu(const ushort* __restrict__ A,
                                                     const ushort* __restrict__ BT,
                                                     ushort* __restrict__ outb) {
  __shared__ ushort lA[2][256 * 64];
  __shared__ ushort lB[2][256 * 64];
  int tid = threadIdx.x, lane = tid & 63, wid = tid >> 6;
  int bid = blockIdx.x;
  int tn = (bid & 7) * 4 + ((bid >> 3) & 3);  // XCD (bid&7) owns 4 tn (B L2-resident)
  int tm = bid >> 5;
  int wm = wid >> 2, wn = wid & 3;
  int lr = lane & 15, lg = lane >> 4;
  const ushort* Ab = A + (size_t)(tm * 256) * 1024;
  const ushort* Bb = BT + (size_t)(tn * 256) * 1024;

  f32x4 acc[8][4];
#pragma unroll
  for (int m = 0; m < 8; ++m)
#pragma unroll
    for (int n = 0; n < 4; ++n) acc[m][n] = (f32x4){0.f, 0.f, 0.f, 0.f};

  int grow = lane >> 3;
  int gsw = (lane & 7) ^ grow;

  auto STG = [&](int bi, int t) {
#pragma unroll
    for (int r = 0; r < 4; ++r) {
      int rb = wid * 4 + r;
      int row = rb * 8 + grow;
      GLOAD_LDS16(Ab + (size_t)row * 1024 + t * 64 + gsw * 8, &lA[bi][rb * 512]);
      GLOAD_LDS16(Bb + (size_t)row * 1024 + t * 64 + gsw * 8, &lB[bi][rb * 512]);
    }
  };

  STG(0, 0);
  STG(1, 1);
  asm volatile("s_waitcnt vmcnt(8)" ::: "memory");
  __builtin_amdgcn_s_barrier();

  for (int t = 0; t < 16; ++t) {
    int c = t & 1;
    const char* bA = (const char*)&lA[c][0];
    const char* bB = (const char*)&lB[c][0];
    bf16x8 bfr[4][2], afh[4][2];
#pragma unroll
    for (int n = 0; n < 4; ++n) {
      int row = wn * 64 + n * 16 + lr;
#pragma unroll
      for (int kk = 0; kk < 2; ++kk)
        bfr[n][kk] = *(const bf16x8*)(bB + row * 128 + ((kk * 64 + lg * 16) ^ ((lr & 7) << 4)));
    }
#pragma unroll
    for (int m = 0; m < 4; ++m) {
      int row = wm * 128 + m * 16 + lr;
#pragma unroll
      for (int kk = 0; kk < 2; ++kk)
        afh[m][kk] = *(const bf16x8*)(bA + row * 128 + ((kk * 64 + lg * 16) ^ ((lr & 7) << 4)));
    }
    __builtin_amdgcn_s_setprio(1);
#pragma unroll
    for (int m = 0; m < 4; ++m)
#pragma unroll
      for (int n = 0; n < 4; ++n)
#pragma unroll
        for (int kk = 0; kk < 2; ++kk)
          acc[m][n] = __builtin_amdgcn_mfma_f32_16x16x32_bf16(afh[m][kk], bfr[n][kk],
                                                              acc[m][n], 0, 0, 0);
    __builtin_amdgcn_s_setprio(0);
#pragma unroll
    for (int m = 0; m < 4; ++m) {
      int row = wm * 128 + 64 + m * 16 + lr;
#pragma unroll
      for (int kk = 0; kk < 2; ++kk)
        afh[m][kk] = *(const bf16x8*)(bA + row * 128 + ((kk * 64 + lg * 16) ^ ((lr & 7) << 4)));
    }
    asm volatile("s_waitcnt lgkmcnt(0)" ::: "memory");
    __builtin_amdgcn_s_barrier();
    if (t + 2 < 16) STG(c, t + 2);
    __builtin_amdgcn_sched_barrier(0);
    __builtin_amdgcn_s_setprio(1);
#pragma unroll
    for (int m = 0; m < 4; ++m)
#pragma unroll
      for (int n = 0; n < 4; ++n)
#pragma unroll
        for (int kk = 0; kk < 2; ++kk)
          acc[4 + m][n] = __builtin_amdgcn_mfma_f32_16x16x32_bf16(afh[m][kk], bfr[n][kk],
                                                                  acc[4 + m][n], 0, 0, 0);
    __builtin_amdgcn_s_setprio(0);
    if (t < 15) {
      if (t + 2 < 16)
        asm volatile("s_waitcnt vmcnt(8)" ::: "memory");
      else
        asm volatile("s_waitcnt vmcnt(0)" ::: "memory");
      __builtin_amdgcn_s_barrier();
    }
  }

#pragma unroll
  for (int m = 0; m < 8; ++m) {
#pragma unroll
    for (int n = 0; n < 4; ++n) {
#pragma unroll
      for (int r = 0; r < 4; ++r) {
        int gr = tm * 256 + wm * 128 + m * 16 + lg * 4 + r;
        int gc = tn * 256 + wn * 64 + n * 16 + lr;
        float val = acc[m][n][r];
        float other = __shfl_xor(val, 1);
        if (!(lane & 1)) {
          float g = val, u = other;
          float a = g / (1.f + __expf(-g)) * u;
          outb[(size_t)gr * (F_DIM) + (gc >> 1)] = f2bf(a);
        }
      }
    }
  }
}

// ---------------- fused: RoPE [0,4096) | V transpose [4096,6144) ----------------
__global__ __launch_bounds__(256) void rope_vtrans(const ushort* __restrict__ qkv,
                                                   const int* __restrict__ rowpos,
                                                   ushort* __restrict__ qr,
                                                   ushort* __restrict__ kr,
                                                   ushort* __restrict__ vt) {
  __shared__ ushort tile[32][33];
  if (blockIdx.x < 4096) {
    int idx = blockIdx.x * 256 + threadIdx.x;
    int i = idx >> 9;
    int rem = idx & 511;
    int h = rem >> 5, d = rem & 31;
    float pos = (float)rowpos[i];
    float inv = __expf(-(float)d * (9.210340371976184f / 32.0f));
    float ang = pos * inv;
    float sn, cs;
    __sincosf(ang, &sn, &cs);
    size_t base = (size_t)i * 3072;
    float q1 = bf2f(qkv[base + h * 64 + d]);
    float q2 = bf2f(qkv[base + h * 64 + 32 + d]);
    float k1 = bf2f(qkv[base + 1024 + h * 64 + d]);
    float k2 = bf2f(qkv[base + 1024 + h * 64 + 32 + d]);
    size_t ob = ((size_t)h * K_TOK + i) * DH_N;
    qr[ob + d] = f2bf((q1 * cs - q2 * sn) * 0.125f);
    qr[ob + 32 + d] = f2bf((q2 * cs + q1 * sn) * 0.125f);
    kr[ob + d] = f2bf(k1 * cs - k2 * sn);
    kr[ob + 32 + d] = f2bf(k2 * cs + k1 * sn);
    return;
  }
  int bid = blockIdx.x - 4096;
  int bx = bid & 63, by = bid >> 6;
  int i0 = bx << 5, c0 = by << 5;
  int tx = threadIdx.x & 31, ty = threadIdx.x >> 5;
#pragma unroll
  for (int j = 0; j < 32; j += 8)
    tile[ty + j][tx] = qkv[(size_t)(i0 + ty + j) * 3072 + 2048 + c0 + tx];
  __syncthreads();
#pragma unroll
  for (int j = 0; j < 32; j += 8)
    vt[(size_t)(c0 + ty + j) * K_TOK + i0 + tx] = tile[tx][ty + j];
}

// ---------------- MFMA flash attention, split-K chunks ----------------
__global__ __launch_bounds__(256) void attn_mfma(const ushort* __restrict__ qr,
                                                 const ushort* __restrict__ kr,
                                                 const ushort* __restrict__ vt,
                                                 ushort* __restrict__ ows,
                                                 float* __restrict__ mlws) {
  __shared__ ushort ktile[2][64 * 64];
  __shared__ ushort vtile[2][64 * 64];
  __shared__ ushort pbuf[4][16 * 64];
  int tid = threadIdx.x, lane = tid & 63, wid = tid >> 6;
  int bid = blockIdx.x;
  int h = bid / 144;
  int rem = 143 - (bid % 144);
  int g = 0;
  while (rem >= 2 * (g + 1) * (g + 2)) ++g;
  int rem2 = rem - 2 * g * (g + 1);
  int qt = (g << 2) + rem2 / (g + 1);
  int ci = rem2 % (g + 1);
  int slot = h * 144 + rem;
  int q0 = qt << 6;
  int t0 = ci << 2;
  int t1 = min(t0 + 3, qt);

  const ushort* Kh = kr + (size_t)h * K_TOK * DH_N;
  const ushort* Vh = vt + (size_t)h * DH_N * K_TOK;
  int lr = lane & 15, lg = lane >> 4;
  int qbase = q0 + wid * 16;

  bf16x8 qf[2];
  const ushort* Qp = qr + ((size_t)h * K_TOK + qbase + lr) * DH_N + lg * 8;
  qf[0] = *(const bf16x8*)(Qp);
  qf[1] = *(const bf16x8*)(Qp + 32);

  f32x4 oa[4];
  float mreg[4], lreg[4];
#pragma unroll
  for (int ct = 0; ct < 4; ++ct) oa[ct] = (f32x4){0.f, 0.f, 0.f, 0.f};
#pragma unroll
  for (int r = 0; r < 4; ++r) { mreg[r] = -1e30f; lreg[r] = 0.f; }

  char* pws = (char*)&pbuf[wid][0];
  int srow8 = lane >> 3, schunk = lane & 7;

  auto stage = [&](int bi, int kb) {
#pragma unroll
    for (int j = 0; j < 2; ++j) {
      int rbase = wid * 16 + j * 8;
      int row = rbase + srow8;
      int gch = schunk ^ (row & 7);
      GLOAD_LDS16(Kh + (size_t)(kb + row) * DH_N + gch * 8, &ktile[bi][rbase * 64]);
      GLOAD_LDS16(Vh + (size_t)row * K_TOK + kb + gch * 8, &vtile[bi][rbase * 64]);
    }
  };

  stage(0, t0 << 6);
  int cur = 0;
  for (int t = t0; t <= t1; ++t) {
    int kb = t << 6;
    __syncthreads();
    if (t < t1) stage(cur ^ 1, (t + 1) << 6);

    const char* kt = (const char*)&ktile[cur][0];
    const char* vtl = (const char*)&vtile[cur][0];

    f32x4 sa[4];
#pragma unroll
    for (int ct = 0; ct < 4; ++ct) sa[ct] = (f32x4){0.f, 0.f, 0.f, 0.f};
#pragma unroll
    for (int s = 0; s < 2; ++s) {
#pragma unroll
      for (int ct = 0; ct < 4; ++ct) {
        int row = ct * 16 + lr;
        bf16x8 kf = *(const bf16x8*)(kt + row * 128 + ((s * 64 + lg * 16) ^ ((row & 7) << 4)));
        sa[ct] = __builtin_amdgcn_mfma_f32_16x16x32_bf16(qf[s], kf, sa[ct], 0, 0, 0);
      }
    }

#pragma unroll
    for (int r = 0; r < 4; ++r) {
      int q = qbase + lg * 4 + r;
      int prow = lg * 4 + r;
      float sv[4];
      float mx = mreg[r];
#pragma unroll
      for (int ct = 0; ct < 4; ++ct) {
        int key = kb + ct * 16 + lr;
        float x = sa[ct][r];
        sv[ct] = (key <= q) ? x : -1e30f;
        mx = fmaxf(mx, sv[ct]);
      }
      mx = fmaxf(mx, __shfl_xor(mx, 1));
      mx = fmaxf(mx, __shfl_xor(mx, 2));
      mx = fmaxf(mx, __shfl_xor(mx, 4));
      mx = fmaxf(mx, __shfl_xor(mx, 8));
      float resc = __expf(mreg[r] - mx);
      float ps = 0.f;
#pragma unroll
      for (int ct = 0; ct < 4; ++ct) {
        float p = __expf(sv[ct] - mx);
        ps += p;
        *(ushort*)(pws + prow * 128 + ((ct * 32 + lr * 2) ^ ((prow & 7) << 4))) = f2bf(p);
      }
      ps += __shfl_xor(ps, 1);
      ps += __shfl_xor(ps, 2);
      ps += __shfl_xor(ps, 4);
      ps += __shfl_xor(ps, 8);
      lreg[r] = lreg[r] * resc + ps;
      mreg[r] = mx;
#pragma unroll
      for (int ct = 0; ct < 4; ++ct) oa[ct][r] *= resc;
    }

    bf16x8 pf[2];
#pragma unroll
    for (int s = 0; s < 2; ++s)
      pf[s] = *(const bf16x8*)(pws + lr * 128 + ((s * 64 + lg * 16) ^ ((lr & 7) << 4)));
#pragma unroll
    for (int s = 0; s < 2; ++s) {
#pragma unroll
      for (int ct = 0; ct < 4; ++ct) {
        int row = ct * 16 + lr;
        bf16x8 vf = *(const bf16x8*)(vtl + row * 128 + ((s * 64 + lg * 16) ^ ((row & 7) << 4)));
        oa[ct] = __builtin_amdgcn_mfma_f32_16x16x32_bf16(pf[s], vf, oa[ct], 0, 0, 0);
      }
    }
    cur ^= 1;
  }

#pragma unroll
  for (int ct = 0; ct < 4; ++ct) {
#pragma unroll
    for (int r = 0; r < 4; ++r) {
      int prow = wid * 16 + lg * 4 + r;
      ows[(size_t)slot * 4096 + prow * 64 + ct * 16 + lr] = f2bf(oa[ct][r]);
    }
  }
  if (lr == 0) {
#pragma unroll
    for (int r = 0; r < 4; ++r) {
      int prow = wid * 16 + lg * 4 + r;
      mlws[(size_t)slot * 128 + prow] = mreg[r];
      mlws[(size_t)slot * 128 + 64 + prow] = lreg[r];
    }
  }
}

// ---------------- combine partial attention chunks ----------------
__global__ __launch_bounds__(256) void attn_combine(const ushort* __restrict__ ows,
                                                    const float* __restrict__ mlws,
                                                    ushort* __restrict__ aout) {
  int bid = blockIdx.x;
  int h = bid & 15, qt = bid >> 4;
  int g = qt >> 2;
  int nc = g + 1;
  int base = h * 144 + 2 * g * (g + 1) + (qt & 3) * nc;
  int tid = threadIdx.x;
  int row = tid >> 2, c0 = (tid & 3) * 16;
  float M = -1e30f;
  for (int i = 0; i < nc; ++i)
    M = fmaxf(M, mlws[(size_t)(base + i) * 128 + row]);
  float L = 0.f;
  float acc[16];
#pragma unroll
  for (int j = 0; j < 16; ++j) acc[j] = 0.f;
  for (int i = 0; i < nc; ++i) {
    size_t sl = (size_t)(base + i);
    float w = __expf(mlws[sl * 128 + row] - M);
    L += mlws[sl * 128 + 64 + row] * w;
    const bf16x8* op = (const bf16x8*)(ows + sl * 4096 + row * 64 + c0);
    bf16x8 v0 = op[0], v1 = op[1];
#pragma unroll
    for (int j = 0; j < 8; ++j) acc[j] += bf2f(((ushort)v0[j])) * w;
#pragma unroll
    for (int j = 0; j < 8; ++j) acc[8 + j] += bf2f(((ushort)v1[j])) * w;
  }
  float inv = 1.f / L;
  int q = qt * 64 + row;
  ushort* dst = aout + (size_t)q * D_DIM + h * DH_N + c0;
#pragma unroll
  for (int j = 0; j < 16; ++j) dst[j] = f2bf(acc[j] * inv);
}

// ---------------- launch ----------------
extern "C" void kernel_launch(void* const* d_in, const int* in_sizes, int n_in,
                              void* d_out, int out_size, void* d_ws, size_t ws_size,
                              hipStream_t stream) {
  const float* hs = (const float*)d_in[0];
  const float* gating = (const float*)d_in[1];
  const int* sel32 = (const int*)d_in[2];
  const int* pos32 = (const int*)d_in[3];
  const float* ln1w = (const float*)d_in[4];
  const float* ln2w = (const float*)d_in[5];
  const float* wq = (const float*)d_in[6];
  const float* bq = (const float*)d_in[7];
  const float* wk = (const float*)d_in[8];
  const float* bk = (const float*)d_in[9];
  const float* wv = (const float*)d_in[10];
  const float* bv = (const float*)d_in[11];
  const float* wo = (const float*)d_in[12];
  const float* wg = (const float*)d_in[13];
  const float* wu = (const float*)d_in[14];
  const float* wd = (const float*)d_in[15];
  float* out = (float*)d_out;

  char* wsb = (char*)d_ws;
  size_t off = 0;
  auto alloc = [&](size_t bytes) -> void* {
    void* p = wsb + off;
    off += (bytes + 255) & ~(size_t)255;
    return p;
  };
  ushort* qkvT = (ushort*)alloc(3072ull * 1024 * 2);
  ushort* woT = (ushort*)alloc(1024ull * 1024 * 2);
  ushort* guT = (ushort*)alloc(8192ull * 1024 * 2);
  ushort* wdT = (ushort*)alloc(1024ull * 4096 * 2);
  float* biasqkv = (float*)alloc(3072 * 4);
  float* xbuf = (float*)alloc(2048ull * 1024 * 4);
  // ---- region A: reused as split-K bf16 partial buffer (dead by gemm1/gemm3) ----
  ushort* hbuf = (ushort*)alloc(2048ull * 1024 * 2);   // slice 0
  ushort* qkv = (ushort*)alloc(2048ull * 3072 * 2);    // slices 1-3 live here
  ushort* qrb = (ushort*)alloc(16ull * 2048 * 64 * 2);
  ushort* krb = (ushort*)alloc(16ull * 2048 * 64 * 2);
  ushort* vtb = (ushort*)alloc(16ull * 64 * 2048 * 2);
  ushort* aoutb = (ushort*)alloc(2048ull * 1024 * 2);
  ushort* pbuf = hbuf;                                  // 4x 4MB bf16 slices
  // ---- region B: x1b/h2b/actb; doubles as attn partial store before rmsnorm_ep1 ----
  float* x1b = (float*)alloc(2048ull * 1024 * 4);
  ushort* h2b = (ushort*)alloc(2048ull * 1024 * 2);
  ushort* actb = (ushort*)alloc(2048ull * 4096 * 2);
  ushort* aows = (ushort*)x1b;
  float* amlws = (float*)((char*)x1b + 2304ull * 4096 * 2);
  float* gbuf = (float*)alloc(2048 * 4);
  int* rowb = (int*)alloc(2048 * 4);
  int* rowt = (int*)alloc(2048 * 4);
  int* rowpos = (int*)alloc(2048 * 4);
  if (off > ws_size) return;

  prep_gather<<<10252, 256, 0, stream>>>(wq, wk, wv, wo, wg, wu, wd, bq, bk, bv, hs, gating,
                                         sel32, pos32, ln1w, qkvT, woT, guT, wdT, biasqkv, out,
                                         xbuf, hbuf, gbuf, rowb, rowt, rowpos);
  gemm_bt<0><<<16 * 24, 256, 0, stream>>>(hbuf, qkvT, 2048, 3072, 1024, 1024, 16 * 24, biasqkv,
                                          qkv);
  rope_vtrans<<<6144, 256, 0, stream>>>(qkv, rowpos, qrb, krb, vtb);
  attn_mfma<<<16 * 144, 256, 0, stream>>>(qrb, krb, vtb, aows, amlws);
  attn_combine<<<512, 256, 0, stream>>>(aows, amlws, aoutb);
  gemm_bt<4><<<2 * 16 * 8, 256, 0, stream>>>(aoutb, woT, 2048, 1024, 1024, 512, 16 * 8, nullptr,
                                             pbuf);
  rmsnorm_ep1<<<2048, 256, 0, stream>>>(xbuf, pbuf, ln2w, x1b, h2b);
  gemm256_gu<<<256, 512, 0, stream>>>(h2b, guT, actb);
  gemm_bt<4><<<4 * 16 * 8, 256, 0, stream>>>(actb, wdT, 2048, 1024, 4096, 1024, 16 * 8, nullptr,
                                             pbuf);
  ep3_k<<<2048, 256, 0, stream>>>(pbuf, x1b, xbuf, gbuf, rowb, rowt, out);
}